// Round 5
// baseline (417.752 us; speedup 1.0000x reference)
//
#include <hip/hip_runtime.h>

#define NODES   304
#define BATCH   128
#define TSTEPS  20
#define HID     64
#define GCNIN   20
#define NN      (BATCH*NODES)      // 38912
#define NE      (NN*16)            // 622592
#define SEG     4
#define SEGSZ   (NN/SEG)           // 9728
#define NSEG    (NN*SEG)           // 155648
#define FC1_IN  (21*NODES)         // 6384
#define KP1     6400               // FC1_IN padded to /32
#define FC1_OUT 2048
#define FC2_OUT 300
#define NP2     304                // FC2_OUT padded to /16
#define BN_EPS  1e-5f

typedef __attribute__((ext_vector_type(8))) short short8;
typedef __attribute__((ext_vector_type(4))) float f32x4;

static __device__ __forceinline__ short f2bf(float x) {
    unsigned u = __float_as_uint(x);
    unsigned r = (u + 0x7FFF + ((u >> 16) & 1)) >> 16;  // RNE
    return (short)r;
}
static __device__ __forceinline__ float bf2f(unsigned short v) {
    return __uint_as_float((unsigned)v << 16);
}

static __device__ __forceinline__ float fast_sigmoid(float q) {
    return __builtin_amdgcn_rcpf(1.f + __expf(-q));
}

// DPP row_ror add (VALU pipe, no DS ops)
template <int C>
static __device__ __forceinline__ float dppadd(float v) {
    return v + __int_as_float(
        __builtin_amdgcn_update_dpp(0, __float_as_int(v), C, 0xF, 0xF, false));
}
static __device__ __forceinline__ float rsum16(float v) {
    v = dppadd<0x128>(v);
    v = dppadd<0x124>(v);
    v = dppadd<0x122>(v);
    v = dppadd<0x121>(v);
    return v;
}

// ---------------- CSR build (segmented by source quarter) ----------------
__global__ void k_count(const int* __restrict__ ei, int* __restrict__ cnt) {
    int e = blockIdx.x * blockDim.x + threadIdx.x;
    if (e < NE) {
        int c = ei[NE + e];
        int half = ei[e] / SEGSZ;
        atomicAdd(&cnt[c * SEG + half], 1);
    }
}

__global__ void k_scan(const int* __restrict__ cnt, int* __restrict__ rowptr,
                       int* __restrict__ cursor) {
    __shared__ int part[1024];
    int tid = threadIdx.x;
    const int CH = NSEG / 1024;  // 152
    int base = tid * CH;
    int s = 0;
    for (int i = 0; i < CH; i++) s += cnt[base + i];
    part[tid] = s;
    __syncthreads();
    for (int d = 1; d < 1024; d <<= 1) {
        int v = (tid >= d) ? part[tid - d] : 0;
        __syncthreads();
        part[tid] += v;
        __syncthreads();
    }
    int run = (tid == 0) ? 0 : part[tid - 1];
    for (int i = 0; i < CH; i++) {
        rowptr[base + i] = run;
        cursor[base + i] = run;
        run += cnt[base + i];
    }
    if (tid == 1023) rowptr[NSEG] = run;
}

__global__ void k_fill(const int* __restrict__ ei, const float* __restrict__ ew,
                       int* __restrict__ cursor, int* __restrict__ row_s,
                       float* __restrict__ w_s) {
    int e = blockIdx.x * blockDim.x + threadIdx.x;
    if (e < NE) {
        int c = ei[NE + e];
        int r = ei[e];
        int slot = atomicAdd(&cursor[c * SEG + r / SEGSZ], 1);
        row_s[slot] = r;
        w_s[slot] = ew[e];
    }
}

__global__ void k_dinv(const int* __restrict__ rowptr, const float* __restrict__ w_s,
                       float* __restrict__ dinv) {
    int c = blockIdx.x * blockDim.x + threadIdx.x;
    if (c < NN) {
        float s = 1.0f;  // self loop weight
        int j1 = rowptr[c * SEG + SEG];
        for (int j = rowptr[c * SEG]; j < j1; j++) s += w_s[j];
        dinv[c] = rsqrtf(fmaxf(s, 1e-12f));
    }
}

// in-place: w_s[j] -> norm_s[j]
__global__ void k_norm(const int* __restrict__ rowptr, const int* __restrict__ row_s,
                       const float* __restrict__ dinv, float* __restrict__ w_s) {
    int c = blockIdx.x * blockDim.x + threadIdx.x;
    if (c < NN) {
        float dc = dinv[c];
        int j1 = rowptr[c * SEG + SEG];
        for (int j = rowptr[c * SEG]; j < j1; j++)
            w_s[j] = dinv[row_s[j]] * w_s[j] * dc;
    }
}

// ---------------- h0 = data_x @ W0 -> bf16 (4 nodes per 256-thr block) ----------
__global__ __launch_bounds__(256) void k_mm20(const float* __restrict__ X,
                                              const float* __restrict__ W,
                                              unsigned short* __restrict__ H) {
    int wv = threadIdx.x >> 6, f = threadIdx.x & 63;
    int n = blockIdx.x * 4 + wv;
    __shared__ float xs[4][GCNIN];
    if (f < GCNIN) xs[wv][f] = X[(size_t)n * GCNIN + f];
    __syncthreads();
    float acc = 0.f;
#pragma unroll
    for (int k = 0; k < GCNIN; k++) acc = fmaf(xs[wv][k], W[k * HID + f], acc);
    H[(size_t)n * HID + f] = (unsigned short)f2bf(acc);
}

// ------- layer0 gather (bf16 feats) + BN + ReLU + fused matvec @W1 -> bf16 -------
__global__ __launch_bounds__(256) void k_gatherA(const int* __restrict__ rowptr,
                                                 const int* __restrict__ row_s,
                                                 const float* __restrict__ norm_s,
                                                 const float* __restrict__ dinv,
                                                 const unsigned short* __restrict__ H0,
                                                 const float* __restrict__ gb,
                                                 const float* __restrict__ bng,
                                                 const float* __restrict__ bnb,
                                                 const float* __restrict__ W1,
                                                 unsigned short* __restrict__ H1) {
    int wv = threadIdx.x >> 6, f = threadIdx.x & 63;
    int c = blockIdx.x * 4 + wv;
    float dc = dinv[c];
    float acc = bf2f(H0[(size_t)c * HID + f]) * dc * dc;  // self loop
    int j1 = rowptr[c * SEG + SEG];
    for (int j = rowptr[c * SEG]; j < j1; j++)
        acc += bf2f(H0[(size_t)row_s[j] * HID + f]) * norm_s[j];
    float scale = bng[f] * rsqrtf(1.f + BN_EPS);
    float y = fmaxf(fmaf(acc + gb[f], scale, bnb[f]), 0.f);  // x1[c][f]

    __shared__ float xs[4][HID];
    xs[wv][f] = y;
    __syncthreads();
    float h = 0.f;
#pragma unroll
    for (int k4 = 0; k4 < HID / 4; k4++) {
        float4 xv = *(const float4*)&xs[wv][k4 * 4];
        h = fmaf(xv.x, W1[(k4 * 4 + 0) * HID + f], h);
        h = fmaf(xv.y, W1[(k4 * 4 + 1) * HID + f], h);
        h = fmaf(xv.z, W1[(k4 * 4 + 2) * HID + f], h);
        h = fmaf(xv.w, W1[(k4 * 4 + 3) * HID + f], h);
    }
    H1[(size_t)c * HID + f] = (unsigned short)f2bf(h);
}

// ---------------- layer1 gather (bf16 feats) + BN + ReLU -> x2 f32 ----------------
__global__ __launch_bounds__(256) void k_gatherB(const int* __restrict__ rowptr,
                                                 const int* __restrict__ row_s,
                                                 const float* __restrict__ norm_s,
                                                 const float* __restrict__ dinv,
                                                 const unsigned short* __restrict__ H,
                                                 const float* __restrict__ gb,
                                                 const float* __restrict__ bng,
                                                 const float* __restrict__ bnb,
                                                 float* __restrict__ XO) {
    int wv = threadIdx.x >> 6, f = threadIdx.x & 63;
    int c = blockIdx.x * 4 + wv;
    float dc = dinv[c];
    float acc = bf2f(H[(size_t)c * HID + f]) * dc * dc;
    int j1 = rowptr[c * SEG + SEG];
    for (int j = rowptr[c * SEG]; j < j1; j++)
        acc += bf2f(H[(size_t)row_s[j] * HID + f]) * norm_s[j];
    float scale = bng[f] * rsqrtf(1.f + BN_EPS);
    XO[(size_t)c * HID + f] = fmaxf(fmaf(acc + gb[f], scale, bnb[f]), 0.f);
}

// ---------------- x2 [38912][64] -> x2t [64][38912] ----------------
__global__ __launch_bounds__(256) void k_xpose(const float* __restrict__ x2,
                                               float* __restrict__ x2t) {
    __shared__ float tile[64][65];
    int n0 = blockIdx.x * 64;
    for (int i = threadIdx.x; i < 4096; i += 256) {
        int r = i >> 6, h = i & 63;
        tile[r][h] = x2[(size_t)(n0 + r) * 64 + h];
    }
    __syncthreads();
    for (int i = threadIdx.x; i < 4096; i += 256) {
        int h = i >> 6, c = i & 63;
        x2t[(size_t)h * NN + n0 + c] = tile[c][h];
    }
}

// ---------------- fused temporal: 16 pairs/block (256 thr), 4 channels/lane ----
// writes bf16 directly into padded GEMM A buffer: Ab[b][t2*304+node]
__global__ __launch_bounds__(256) void k_temporal2(
    const float* __restrict__ data_x, const float* __restrict__ x2t,
    const float* __restrict__ w1, const float* __restrict__ b1,
    const float* __restrict__ w2, const float* __restrict__ b2,
    const float* __restrict__ w3, const float* __restrict__ b3,
    const float* __restrict__ v1, const float* __restrict__ vb1,
    const float* __restrict__ v2, const float* __restrict__ vb2,
    const float* __restrict__ v3, const float* __restrict__ vb3,
    const float* __restrict__ bn2g, const float* __restrict__ bn2b,
    short* __restrict__ Ab) {
    int bn0 = blockIdx.x * 16;
    int b = bn0 / NODES, node0 = bn0 % NODES;  // 304%16==0: never straddles b
    int tid = threadIdx.x;
    int p = tid >> 4;            // pair 0..15
    int c0 = (tid & 15) << 2;    // channel base (4 channels/lane)
    int node = node0 + p;

    __shared__ float xs[16][22];
    for (int i = tid; i < 320; i += 256) {
        int t = i >> 4, pp = i & 15;
        xs[pp][t + 1] = data_x[b * (TSTEPS * NODES) + t * NODES + node0 + pp];
    }
    if (tid < 16) { xs[tid][0] = 0.f; xs[tid][21] = 0.f; }

    float A1[4][3], A2[4][3], A3[4][3], B1v[4], B2v[4], B3v[4];
    float U1[4][3], U2[4][3], U3[4][3];
#pragma unroll
    for (int i = 0; i < 4; i++) {
        int c = c0 + i;
#pragma unroll
        for (int k = 0; k < 3; k++) {
            A1[i][k] = w1[c * 3 + k];
            A2[i][k] = w2[c * 3 + k];
            A3[i][k] = w3[c * 3 + k];
            U1[i][k] = v1[c * 3 + k];
            U2[i][k] = v2[c * 3 + k];
            U3[i][k] = v3[c * 3 + k];
        }
        B1v[i] = b1[c];
        B2v[i] = b2[c];
        B3v[i] = b3[c];
    }
    float cb1 = vb1[0], cb2 = vb2[0], cb3 = vb3[0];
    float s2 = bn2g[node] * rsqrtf(1.f + BN_EPS);
    float bb2 = bn2b[node];
    short* dst = Ab + (size_t)b * KP1;

    __syncthreads();

    float hA[4] = {0.f, 0.f, 0.f, 0.f}, hB[4] = {0.f, 0.f, 0.f, 0.f}, hC[4];
    float xr0 = xs[p][0], xr1 = xs[p][1];

#pragma unroll
    for (int j = 0; j <= 21; j++) {
        if (j < 20) {
            float xr2 = xs[p][j + 2];
#pragma unroll
            for (int i = 0; i < 4; i++) {
                float pv = fmaf(A1[i][2], xr2, fmaf(A1[i][1], xr1, fmaf(A1[i][0], xr0, B1v[i])));
                float qv = fmaf(A2[i][2], xr2, fmaf(A2[i][1], xr1, fmaf(A2[i][0], xr0, B2v[i])));
                float rv = fmaf(A3[i][2], xr2, fmaf(A3[i][1], xr1, fmaf(A3[i][0], xr0, B3v[i])));
                hC[i] = fmaxf(fmaf(pv, fast_sigmoid(qv), rv), 0.f);
            }
            xr0 = xr1;
            xr1 = xr2;
        } else if (j == 20) {
            const float4 gv = *(const float4*)(x2t + (size_t)(b >> 1) * NN +
                                               (b & 1) * (NODES * HID) + node * HID + c0);
            hC[0] = fmaxf(gv.x, 0.f);
            hC[1] = fmaxf(gv.y, 0.f);
            hC[2] = fmaxf(gv.z, 0.f);
            hC[3] = fmaxf(gv.w, 0.f);
        } else {
#pragma unroll
            for (int i = 0; i < 4; i++) hC[i] = 0.f;
        }
        if (j >= 1) {
            int w = j - 1;
            float pp_ = 0.f, qq_ = 0.f, rr_ = 0.f;
#pragma unroll
            for (int i = 0; i < 4; i++) {
                pp_ = fmaf(U1[i][0], hA[i], pp_);
                pp_ = fmaf(U1[i][1], hB[i], pp_);
                pp_ = fmaf(U1[i][2], hC[i], pp_);
                qq_ = fmaf(U2[i][0], hA[i], qq_);
                qq_ = fmaf(U2[i][1], hB[i], qq_);
                qq_ = fmaf(U2[i][2], hC[i], qq_);
                rr_ = fmaf(U3[i][0], hA[i], rr_);
                rr_ = fmaf(U3[i][1], hB[i], rr_);
                rr_ = fmaf(U3[i][2], hC[i], rr_);
            }
            pp_ = rsum16(pp_);
            qq_ = rsum16(qq_);
            rr_ = rsum16(rr_);
            float P = pp_ + cb1, Q = qq_ + cb2, R = rr_ + cb3;
            float hv = fmaxf(fmaf(P, fast_sigmoid(Q), R), 0.f);
            if ((tid & 15) == 0) dst[w * NODES + node] = f2bf(fmaf(hv, s2, bb2));
        }
#pragma unroll
        for (int i = 0; i < 4; i++) {
            hA[i] = hB[i];
            hB[i] = hC[i];
        }
    }
}

// fc4W [2048][300] f32 -> W4t [304][2048] bf16 (transposed, N-padded)
__global__ __launch_bounds__(256) void k_cvtW4(const float* __restrict__ W,
                                               short* __restrict__ Wt) {
    __shared__ float t[32][33];
    int tx = threadIdx.x & 31, ty = threadIdx.x >> 5;
    int n0 = blockIdx.x * 32, k0 = blockIdx.y * 32;
#pragma unroll
    for (int r = 0; r < 32; r += 8) {
        int k = k0 + r + ty, n = n0 + tx;
        t[r + ty][tx] = (n < FC2_OUT) ? W[(size_t)k * FC2_OUT + n] : 0.f;
    }
    __syncthreads();
#pragma unroll
    for (int r = 0; r < 32; r += 8) {
        int n = n0 + r + ty;
        if (n < NP2) Wt[(size_t)n * FC1_OUT + k0 + tx] = f2bf(t[tx][r + ty]);
    }
}

// ---------------- FC1 MFMA GEMM, B read directly from f32 fcW ----------------
#define KSPL1 8
#define KCH1  (KP1 / KSPL1)  // 800
__global__ __launch_bounds__(256) void k_gemm1f(const short* __restrict__ Ab,
                                                const float* __restrict__ fcW,
                                                float* __restrict__ part) {
    int lane = threadIdx.x & 63, wv = threadIdx.x >> 6;
    int r = lane & 15, kg = lane >> 4;
    int nb = blockIdx.x * 64, sp = blockIdx.y;

    f32x4 acc[2][4] = {};
    const short* a0 = Ab + (size_t)(wv * 32 + r) * KP1;
    const short* a1 = a0 + (size_t)16 * KP1;

    int k0 = sp * KCH1 + kg * 8;
    const float* wp = fcW + (size_t)k0 * FC1_OUT + nb + r;
    bool tailblk = (sp == KSPL1 - 1);

#pragma unroll 1
    for (int s = 0; s < KCH1 / 32; s++, k0 += 32) {
        short8 av0 = *(const short8*)(a0 + k0);
        short8 av1 = *(const short8*)(a1 + k0);
        short8 bv[4];
        if (tailblk && s == KCH1 / 32 - 1) {
#pragma unroll
            for (int f = 0; f < 4; f++)
#pragma unroll
                for (int i = 0; i < 8; i++) {
                    float v = (k0 + i < FC1_IN) ? wp[(size_t)i * FC1_OUT + f * 16] : 0.f;
                    bv[f][i] = f2bf(v);
                }
        } else {
#pragma unroll
            for (int f = 0; f < 4; f++)
#pragma unroll
                for (int i = 0; i < 8; i++)
                    bv[f][i] = f2bf(wp[(size_t)i * FC1_OUT + f * 16]);
        }
        acc[0][0] = __builtin_amdgcn_mfma_f32_16x16x32_bf16(av0, bv[0], acc[0][0], 0, 0, 0);
        acc[1][0] = __builtin_amdgcn_mfma_f32_16x16x32_bf16(av1, bv[0], acc[1][0], 0, 0, 0);
        acc[0][1] = __builtin_amdgcn_mfma_f32_16x16x32_bf16(av0, bv[1], acc[0][1], 0, 0, 0);
        acc[1][1] = __builtin_amdgcn_mfma_f32_16x16x32_bf16(av1, bv[1], acc[1][1], 0, 0, 0);
        acc[0][2] = __builtin_amdgcn_mfma_f32_16x16x32_bf16(av0, bv[2], acc[0][2], 0, 0, 0);
        acc[1][2] = __builtin_amdgcn_mfma_f32_16x16x32_bf16(av1, bv[2], acc[1][2], 0, 0, 0);
        acc[0][3] = __builtin_amdgcn_mfma_f32_16x16x32_bf16(av0, bv[3], acc[0][3], 0, 0, 0);
        acc[1][3] = __builtin_amdgcn_mfma_f32_16x16x32_bf16(av1, bv[3], acc[1][3], 0, 0, 0);
        wp += (size_t)32 * FC1_OUT;
    }

    float* dst = part + (size_t)sp * BATCH * FC1_OUT;
#pragma unroll
    for (int m = 0; m < 2; m++)
#pragma unroll
        for (int f = 0; f < 4; f++)
#pragma unroll
            for (int j = 0; j < 4; j++) {
                int row = wv * 32 + m * 16 + kg * 4 + j;
                int col = nb + f * 16 + r;
                dst[(size_t)row * FC1_OUT + col] = acc[m][f][j];
            }
}

// reduce split-K + bias + ReLU -> bf16 activations for FC2
__global__ __launch_bounds__(256) void k_reduce1(const float* __restrict__ part,
                                                 const float* __restrict__ bias,
                                                 short* __restrict__ Ab2) {
    int idx = blockIdx.x * 256 + threadIdx.x;
    int o = idx & (FC1_OUT - 1);
    float s = bias[o];
#pragma unroll
    for (int sp = 0; sp < KSPL1; sp++) s += part[(size_t)sp * BATCH * FC1_OUT + idx];
    Ab2[idx] = f2bf(fmaxf(s, 0.f));
}

// ---------------- FC2 MFMA GEMM ----------------
#define KSPL2 8
#define KCH2  (FC1_OUT / KSPL2)  // 256
__global__ __launch_bounds__(256) void k_gemm2(const short* __restrict__ Ab,
                                               const short* __restrict__ Wt,
                                               float* __restrict__ part) {
    int lane = threadIdx.x & 63, wv = threadIdx.x >> 6;
    int r = lane & 15, kg = lane >> 4;
    int nb = blockIdx.x * 16, sp = blockIdx.y;

    f32x4 acc[2] = {};
    const short* a0 = Ab + (size_t)(wv * 32 + r) * FC1_OUT;
    const short* a1 = a0 + (size_t)16 * FC1_OUT;
    const short* bp = Wt + (size_t)(nb + r) * FC1_OUT;

    int k0 = sp * KCH2 + kg * 8;
#pragma unroll
    for (int s = 0; s < KCH2 / 32; s++, k0 += 32) {
        short8 av0 = *(const short8*)(a0 + k0);
        short8 av1 = *(const short8*)(a1 + k0);
        short8 bv = *(const short8*)(bp + k0);
        acc[0] = __builtin_amdgcn_mfma_f32_16x16x32_bf16(av0, bv, acc[0], 0, 0, 0);
        acc[1] = __builtin_amdgcn_mfma_f32_16x16x32_bf16(av1, bv, acc[1], 0, 0, 0);
    }

    float* dst = part + (size_t)sp * BATCH * NP2;
#pragma unroll
    for (int m = 0; m < 2; m++)
#pragma unroll
        for (int j = 0; j < 4; j++) {
            int row = wv * 32 + m * 16 + kg * 4 + j;
            int col = nb + r;
            dst[(size_t)row * NP2 + col] = acc[m][j];
        }
}

__global__ __launch_bounds__(256) void k_reduce2(const float* __restrict__ part,
                                                 const float* __restrict__ bias,
                                                 float* __restrict__ out) {
    int idx = blockIdx.x * 256 + threadIdx.x;
    if (idx >= BATCH * NP2) return;
    int b = idx / NP2, o = idx % NP2;
    float s = 0.f;
#pragma unroll
    for (int sp = 0; sp < KSPL2; sp++) s += part[(size_t)sp * BATCH * NP2 + idx];
    if (o < FC2_OUT) out[(size_t)b * FC2_OUT + o] = s + bias[o];
}

extern "C" void kernel_launch(void* const* d_in, const int* in_sizes, int n_in,
                              void* d_out, int out_size, void* d_ws, size_t ws_size,
                              hipStream_t stream) {
    const float* data_x = (const float*)d_in[0];
    const int* ei = (const int*)d_in[1];
    const float* ew = (const float*)d_in[2];
    const float* tc1w1 = (const float*)d_in[3];
    const float* tc1b1 = (const float*)d_in[4];
    const float* tc1w2 = (const float*)d_in[5];
    const float* tc1b2 = (const float*)d_in[6];
    const float* tc1w3 = (const float*)d_in[7];
    const float* tc1b3 = (const float*)d_in[8];
    const float* W0 = (const float*)d_in[9];
    const float* gb0 = (const float*)d_in[10];
    const float* bn0g = (const float*)d_in[11];
    const float* bn0b = (const float*)d_in[12];
    const float* W1 = (const float*)d_in[13];
    const float* gb1 = (const float*)d_in[14];
    const float* bn1g = (const float*)d_in[15];
    const float* bn1b = (const float*)d_in[16];
    const float* tc2w1 = (const float*)d_in[17];
    const float* tc2b1 = (const float*)d_in[18];
    const float* tc2w2 = (const float*)d_in[19];
    const float* tc2b2 = (const float*)d_in[20];
    const float* tc2w3 = (const float*)d_in[21];
    const float* tc2b3 = (const float*)d_in[22];
    const float* bn2g = (const float*)d_in[23];
    const float* bn2b = (const float*)d_in[24];
    const float* fcW = (const float*)d_in[25];
    const float* fcb = (const float*)d_in[26];
    const float* fc4W = (const float*)d_in[27];
    const float* fc4b = (const float*)d_in[28];
    float* out = (float*)d_out;

    char* ws = (char*)d_ws;
    // persistent region: x2 (gfeat source) + Ab (FC1 bf16 activations)
    float* x2 = (float*)(ws + 0);                  // 9,961,472 B
    short* Ab = (short*)(ws + 9961472);            // 1,638,400 B
    const size_t ARENA = 9961472 + 1638400;        // 11,599,872

    // arena A (CSR/GCN phase)
    size_t off = ARENA;
    auto alloc = [&](size_t bytes) -> void* {
        void* p = ws + off;
        off = (off + bytes + 255) & ~(size_t)255;
        return p;
    };
    int* cnt = (int*)alloc((size_t)NSEG * 4);
    int* rowptr = (int*)alloc((size_t)(NSEG + 1) * 4);
    int* cursor = (int*)alloc((size_t)NSEG * 4);
    int* row_s = (int*)alloc((size_t)NE * 4);
    float* w_s = (float*)alloc((size_t)NE * 4);
    float* dinv = (float*)alloc((size_t)NN * 4);
    unsigned short* h0 = (unsigned short*)alloc((size_t)NN * HID * 2);
    unsigned short* h1 = (unsigned short*)alloc((size_t)NN * HID * 2);

    // x2t overlaps arena A (written by k_xpose AFTER all CSR/GCN consumers done)
    float* x2t = (float*)(ws + ARENA);             // 9,961,472 B

    // arena C (FC phase) — overlaps arena A and x2t, used only after temporal
    off = ARENA;
    float* part1 = (float*)alloc((size_t)KSPL1 * BATCH * FC1_OUT * 4);
    short* Ab2 = (short*)alloc((size_t)BATCH * FC1_OUT * 2);
    short* W4t = (short*)alloc((size_t)NP2 * FC1_OUT * 2);
    float* part2 = (float*)alloc((size_t)KSPL2 * BATCH * NP2 * 4);
    (void)ws_size; (void)in_sizes; (void)n_in; (void)out_size;

    // ---- CSR (source-segmented) ----
    hipMemsetAsync(cnt, 0, (size_t)NSEG * 4, stream);
    k_count<<<(NE + 255) / 256, 256, 0, stream>>>(ei, cnt);
    k_scan<<<1, 1024, 0, stream>>>(cnt, rowptr, cursor);
    k_fill<<<(NE + 255) / 256, 256, 0, stream>>>(ei, ew, cursor, row_s, w_s);
    k_dinv<<<(NN + 255) / 256, 256, 0, stream>>>(rowptr, w_s, dinv);
    k_norm<<<(NN + 255) / 256, 256, 0, stream>>>(rowptr, row_s, dinv, w_s);

    // ---- GCN (bf16 gathered features) ----
    k_mm20<<<NN / 4, 256, 0, stream>>>(data_x, W0, h0);
    k_gatherA<<<NN / 4, 256, 0, stream>>>(rowptr, row_s, w_s, dinv, h0, gb0, bn0g,
                                          bn0b, W1, h1);
    k_gatherB<<<NN / 4, 256, 0, stream>>>(rowptr, row_s, w_s, dinv, h1, gb1, bn1g,
                                          bn1b, x2);

    // ---- transpose x2 for coalesced gfeat ----
    k_xpose<<<NN / 64, 256, 0, stream>>>(x2, x2t);

    // ---- temporal (fused conv1 + concat + conv2 + BN2d) -> bf16 Ab ----
    hipMemsetAsync(Ab, 0, (size_t)BATCH * KP1 * 2, stream);  // zero K-padding
    k_temporal2<<<NN / 16, 256, 0, stream>>>(data_x, x2t, tc1w1, tc1b1, tc1w2, tc1b2,
                                             tc1w3, tc1b3, tc2w1, tc2b1, tc2w2, tc2b2,
                                             tc2w3, tc2b3, bn2g, bn2b, Ab);

    // ---- FC (bf16 MFMA) ----
    {
        dim3 g(FC1_OUT / 64, KSPL1);
        k_gemm1f<<<g, 256, 0, stream>>>(Ab, fcW, part1);
    }
    k_reduce1<<<BATCH * FC1_OUT / 256, 256, 0, stream>>>(part1, fcb, Ab2);
    {
        dim3 g((NP2 + 31) / 32, FC1_OUT / 32);
        k_cvtW4<<<g, 256, 0, stream>>>(fc4W, W4t);
    }
    {
        dim3 g(NP2 / 16, KSPL2);
        k_gemm2<<<g, 256, 0, stream>>>(Ab2, W4t, part2);
    }
    k_reduce2<<<(BATCH * NP2 + 255) / 256, 256, 0, stream>>>(part2, fc4b, out);
}

// Round 6
// 276.969 us; speedup vs baseline: 1.5083x; 1.5083x over previous
//
#include <hip/hip_runtime.h>

#define NODES   304
#define BATCH   128
#define TSTEPS  20
#define HID     64
#define GCNIN   20
#define NN      (BATCH*NODES)      // 38912
#define NE      (NN*16)            // 622592
#define SEG     4
#define SEGSZ   (NN/SEG)           // 9728
#define NSEG    (NN*SEG)           // 155648
#define NB_SCAN (NSEG/256)         // 608
#define FC1_IN  (21*NODES)         // 6384
#define KP1     6400               // FC1_IN padded to /32
#define FC1_OUT 2048
#define FC2_OUT 300
#define NP2     304                // FC2_OUT padded to /16
#define BN_EPS  1e-5f

typedef __attribute__((ext_vector_type(8))) short short8;
typedef __attribute__((ext_vector_type(4))) float f32x4;

static __device__ __forceinline__ short f2bf(float x) {
    unsigned u = __float_as_uint(x);
    unsigned r = (u + 0x7FFF + ((u >> 16) & 1)) >> 16;  // RNE
    return (short)r;
}
static __device__ __forceinline__ float bf2f(unsigned short v) {
    return __uint_as_float((unsigned)v << 16);
}

static __device__ __forceinline__ float fast_sigmoid(float q) {
    return __builtin_amdgcn_rcpf(1.f + __expf(-q));
}

// DPP row_ror add (VALU pipe, no DS ops)
template <int C>
static __device__ __forceinline__ float dppadd(float v) {
    return v + __int_as_float(
        __builtin_amdgcn_update_dpp(0, __float_as_int(v), C, 0xF, 0xF, false));
}
static __device__ __forceinline__ float rsum16(float v) {
    v = dppadd<0x128>(v);
    v = dppadd<0x124>(v);
    v = dppadd<0x122>(v);
    v = dppadd<0x121>(v);
    return v;
}

// ---------------- CSR build (segmented by source quarter) ----------------
__global__ void k_count(const int* __restrict__ ei, int* __restrict__ cnt) {
    int e = blockIdx.x * blockDim.x + threadIdx.x;
    if (e < NE) {
        int c = ei[NE + e];
        int half = ei[e] / SEGSZ;
        atomicAdd(&cnt[c * SEG + half], 1);
    }
}

// 3-kernel exclusive scan over cnt[NSEG] -> rowptr/cursor
__global__ __launch_bounds__(256) void k_scan1(const int* __restrict__ cnt,
                                               int* __restrict__ rel,
                                               int* __restrict__ bsum) {
    __shared__ int s[256];
    int tid = threadIdx.x;
    int g = blockIdx.x * 256 + tid;
    int v = cnt[g];
    s[tid] = v;
    __syncthreads();
    for (int d = 1; d < 256; d <<= 1) {
        int t = (tid >= d) ? s[tid - d] : 0;
        __syncthreads();
        s[tid] += t;
        __syncthreads();
    }
    rel[g] = s[tid] - v;  // exclusive within block
    if (tid == 255) bsum[blockIdx.x] = s[255];
}

__global__ __launch_bounds__(1024) void k_scan2(int* __restrict__ bsum) {
    __shared__ int s[1024];
    int tid = threadIdx.x;
    int v = (tid < NB_SCAN) ? bsum[tid] : 0;
    s[tid] = v;
    __syncthreads();
    for (int d = 1; d < 1024; d <<= 1) {
        int t = (tid >= d) ? s[tid - d] : 0;
        __syncthreads();
        s[tid] += t;
        __syncthreads();
    }
    if (tid < NB_SCAN) bsum[tid] = s[tid] - v;  // exclusive block offsets
}

__global__ __launch_bounds__(256) void k_scan3(int* __restrict__ rowptr,
                                               const int* __restrict__ bsum,
                                               int* __restrict__ cursor) {
    int g = blockIdx.x * 256 + threadIdx.x;
    int val = rowptr[g] + bsum[blockIdx.x];
    rowptr[g] = val;
    cursor[g] = val;
    if (g == 0) rowptr[NSEG] = NE;
}

__global__ void k_fill(const int* __restrict__ ei, const float* __restrict__ ew,
                       int* __restrict__ cursor, int* __restrict__ row_s,
                       float* __restrict__ w_s) {
    int e = blockIdx.x * blockDim.x + threadIdx.x;
    if (e < NE) {
        int c = ei[NE + e];
        int r = ei[e];
        int slot = atomicAdd(&cursor[c * SEG + r / SEGSZ], 1);
        row_s[slot] = r;
        w_s[slot] = ew[e];
    }
}

__global__ void k_dinv(const int* __restrict__ rowptr, const float* __restrict__ w_s,
                       float* __restrict__ dinv) {
    int c = blockIdx.x * blockDim.x + threadIdx.x;
    if (c < NN) {
        float s = 1.0f;  // self loop weight
        int j1 = rowptr[c * SEG + SEG];
        for (int j = rowptr[c * SEG]; j < j1; j++) s += w_s[j];
        dinv[c] = rsqrtf(fmaxf(s, 1e-12f));
    }
}

// in-place: w_s[j] -> norm_s[j]   (8-deep MLP on the dinv gather)
__global__ void k_norm(const int* __restrict__ rowptr, const int* __restrict__ row_s,
                       const float* __restrict__ dinv, float* __restrict__ w_s) {
    int c = blockIdx.x * blockDim.x + threadIdx.x;
    if (c >= NN) return;
    float dc = dinv[c];
    int j0 = rowptr[c * SEG], j1 = rowptr[c * SEG + SEG];
    for (int j = j0; j < j1; j += 8) {
        int id[8];
#pragma unroll
        for (int i = 0; i < 8; i++) {
            int jj = (j + i < j1) ? j + i : j1 - 1;
            id[i] = row_s[jj];
        }
        float dv[8];
#pragma unroll
        for (int i = 0; i < 8; i++) dv[i] = dinv[id[i]];
#pragma unroll
        for (int i = 0; i < 8; i++)
            if (j + i < j1) w_s[j + i] = dv[i] * w_s[j + i] * dc;
    }
}

// ---------------- h0 = data_x @ W0 -> bf16 (4 nodes per 256-thr block) ----------
__global__ __launch_bounds__(256) void k_mm20(const float* __restrict__ X,
                                              const float* __restrict__ W,
                                              unsigned short* __restrict__ H) {
    int wv = threadIdx.x >> 6, f = threadIdx.x & 63;
    int n = blockIdx.x * 4 + wv;
    __shared__ float xs[4][GCNIN];
    if (f < GCNIN) xs[wv][f] = X[(size_t)n * GCNIN + f];
    __syncthreads();
    float acc = 0.f;
#pragma unroll
    for (int k = 0; k < GCNIN; k++) acc = fmaf(xs[wv][k], W[k * HID + f], acc);
    H[(size_t)n * HID + f] = (unsigned short)f2bf(acc);
}

// ------- layer0 gather (bf16, 8-deep MLP) + BN + ReLU + matvec @W1 -> bf16 -------
__global__ __launch_bounds__(256) void k_gatherA(const int* __restrict__ rowptr,
                                                 const int* __restrict__ row_s,
                                                 const float* __restrict__ norm_s,
                                                 const float* __restrict__ dinv,
                                                 const unsigned short* __restrict__ H0,
                                                 const float* __restrict__ gb,
                                                 const float* __restrict__ bng,
                                                 const float* __restrict__ bnb,
                                                 const float* __restrict__ W1,
                                                 unsigned short* __restrict__ H1) {
    int wv = threadIdx.x >> 6, f = threadIdx.x & 63;
    int c = blockIdx.x * 4 + wv;
    float dc = dinv[c];
    float acc = bf2f(H0[(size_t)c * HID + f]) * dc * dc;  // self loop
    int j0 = rowptr[c * SEG], j1 = rowptr[c * SEG + SEG];
    for (int j = j0; j < j1; j += 8) {
        int idx[8];
        float w[8];
#pragma unroll
        for (int i = 0; i < 8; i++) {
            int jj = (j + i < j1) ? j + i : j1 - 1;
            idx[i] = row_s[jj];
            w[i] = (j + i < j1) ? norm_s[jj] : 0.f;
        }
        float v[8];
#pragma unroll
        for (int i = 0; i < 8; i++) v[i] = bf2f(H0[(size_t)idx[i] * HID + f]);
#pragma unroll
        for (int i = 0; i < 8; i++) acc = fmaf(v[i], w[i], acc);
    }
    float scale = bng[f] * rsqrtf(1.f + BN_EPS);
    float y = fmaxf(fmaf(acc + gb[f], scale, bnb[f]), 0.f);  // x1[c][f]

    __shared__ float xs[4][HID];
    xs[wv][f] = y;
    __syncthreads();
    float h = 0.f;
#pragma unroll
    for (int k4 = 0; k4 < HID / 4; k4++) {
        float4 xv = *(const float4*)&xs[wv][k4 * 4];
        h = fmaf(xv.x, W1[(k4 * 4 + 0) * HID + f], h);
        h = fmaf(xv.y, W1[(k4 * 4 + 1) * HID + f], h);
        h = fmaf(xv.z, W1[(k4 * 4 + 2) * HID + f], h);
        h = fmaf(xv.w, W1[(k4 * 4 + 3) * HID + f], h);
    }
    H1[(size_t)c * HID + f] = (unsigned short)f2bf(h);
}

// -------- layer1 gather (bf16, 8-deep MLP) + BN + ReLU -> x2 f32 --------
__global__ __launch_bounds__(256) void k_gatherB(const int* __restrict__ rowptr,
                                                 const int* __restrict__ row_s,
                                                 const float* __restrict__ norm_s,
                                                 const float* __restrict__ dinv,
                                                 const unsigned short* __restrict__ H,
                                                 const float* __restrict__ gb,
                                                 const float* __restrict__ bng,
                                                 const float* __restrict__ bnb,
                                                 float* __restrict__ XO) {
    int wv = threadIdx.x >> 6, f = threadIdx.x & 63;
    int c = blockIdx.x * 4 + wv;
    float dc = dinv[c];
    float acc = bf2f(H[(size_t)c * HID + f]) * dc * dc;
    int j0 = rowptr[c * SEG], j1 = rowptr[c * SEG + SEG];
    for (int j = j0; j < j1; j += 8) {
        int idx[8];
        float w[8];
#pragma unroll
        for (int i = 0; i < 8; i++) {
            int jj = (j + i < j1) ? j + i : j1 - 1;
            idx[i] = row_s[jj];
            w[i] = (j + i < j1) ? norm_s[jj] : 0.f;
        }
        float v[8];
#pragma unroll
        for (int i = 0; i < 8; i++) v[i] = bf2f(H[(size_t)idx[i] * HID + f]);
#pragma unroll
        for (int i = 0; i < 8; i++) acc = fmaf(v[i], w[i], acc);
    }
    float scale = bng[f] * rsqrtf(1.f + BN_EPS);
    XO[(size_t)c * HID + f] = fmaxf(fmaf(acc + gb[f], scale, bnb[f]), 0.f);
}

// ---------------- x2 [38912][64] -> x2t [64][38912] ----------------
__global__ __launch_bounds__(256) void k_xpose(const float* __restrict__ x2,
                                               float* __restrict__ x2t) {
    __shared__ float tile[64][65];
    int n0 = blockIdx.x * 64;
    for (int i = threadIdx.x; i < 4096; i += 256) {
        int r = i >> 6, h = i & 63;
        tile[r][h] = x2[(size_t)(n0 + r) * 64 + h];
    }
    __syncthreads();
    for (int i = threadIdx.x; i < 4096; i += 256) {
        int h = i >> 6, c = i & 63;
        x2t[(size_t)h * NN + n0 + c] = tile[c][h];
    }
}

// ---------------- fused temporal: 16 pairs/block (256 thr), 4 channels/lane ----
// writes bf16 directly into padded GEMM A buffer: Ab[b][t2*304+node]
__global__ __launch_bounds__(256) void k_temporal2(
    const float* __restrict__ data_x, const float* __restrict__ x2t,
    const float* __restrict__ w1, const float* __restrict__ b1,
    const float* __restrict__ w2, const float* __restrict__ b2,
    const float* __restrict__ w3, const float* __restrict__ b3,
    const float* __restrict__ v1, const float* __restrict__ vb1,
    const float* __restrict__ v2, const float* __restrict__ vb2,
    const float* __restrict__ v3, const float* __restrict__ vb3,
    const float* __restrict__ bn2g, const float* __restrict__ bn2b,
    short* __restrict__ Ab) {
    int bn0 = blockIdx.x * 16;
    int b = bn0 / NODES, node0 = bn0 % NODES;  // 304%16==0: never straddles b
    int tid = threadIdx.x;
    int p = tid >> 4;            // pair 0..15
    int c0 = (tid & 15) << 2;    // channel base (4 channels/lane)
    int node = node0 + p;

    __shared__ float xs[16][22];
    for (int i = tid; i < 320; i += 256) {
        int t = i >> 4, pp = i & 15;
        xs[pp][t + 1] = data_x[b * (TSTEPS * NODES) + t * NODES + node0 + pp];
    }
    if (tid < 16) { xs[tid][0] = 0.f; xs[tid][21] = 0.f; }

    float A1[4][3], A2[4][3], A3[4][3], B1v[4], B2v[4], B3v[4];
    float U1[4][3], U2[4][3], U3[4][3];
#pragma unroll
    for (int i = 0; i < 4; i++) {
        int c = c0 + i;
#pragma unroll
        for (int k = 0; k < 3; k++) {
            A1[i][k] = w1[c * 3 + k];
            A2[i][k] = w2[c * 3 + k];
            A3[i][k] = w3[c * 3 + k];
            U1[i][k] = v1[c * 3 + k];
            U2[i][k] = v2[c * 3 + k];
            U3[i][k] = v3[c * 3 + k];
        }
        B1v[i] = b1[c];
        B2v[i] = b2[c];
        B3v[i] = b3[c];
    }
    float cb1 = vb1[0], cb2 = vb2[0], cb3 = vb3[0];
    float s2 = bn2g[node] * rsqrtf(1.f + BN_EPS);
    float bb2 = bn2b[node];
    short* dst = Ab + (size_t)b * KP1;

    __syncthreads();

    float hA[4] = {0.f, 0.f, 0.f, 0.f}, hB[4] = {0.f, 0.f, 0.f, 0.f}, hC[4];
    float xr0 = xs[p][0], xr1 = xs[p][1];

#pragma unroll
    for (int j = 0; j <= 21; j++) {
        if (j < 20) {
            float xr2 = xs[p][j + 2];
#pragma unroll
            for (int i = 0; i < 4; i++) {
                float pv = fmaf(A1[i][2], xr2, fmaf(A1[i][1], xr1, fmaf(A1[i][0], xr0, B1v[i])));
                float qv = fmaf(A2[i][2], xr2, fmaf(A2[i][1], xr1, fmaf(A2[i][0], xr0, B2v[i])));
                float rv = fmaf(A3[i][2], xr2, fmaf(A3[i][1], xr1, fmaf(A3[i][0], xr0, B3v[i])));
                hC[i] = fmaxf(fmaf(pv, fast_sigmoid(qv), rv), 0.f);
            }
            xr0 = xr1;
            xr1 = xr2;
        } else if (j == 20) {
            const float4 gv = *(const float4*)(x2t + (size_t)(b >> 1) * NN +
                                               (b & 1) * (NODES * HID) + node * HID + c0);
            hC[0] = fmaxf(gv.x, 0.f);
            hC[1] = fmaxf(gv.y, 0.f);
            hC[2] = fmaxf(gv.z, 0.f);
            hC[3] = fmaxf(gv.w, 0.f);
        } else {
#pragma unroll
            for (int i = 0; i < 4; i++) hC[i] = 0.f;
        }
        if (j >= 1) {
            int w = j - 1;
            float pp_ = 0.f, qq_ = 0.f, rr_ = 0.f;
#pragma unroll
            for (int i = 0; i < 4; i++) {
                pp_ = fmaf(U1[i][0], hA[i], pp_);
                pp_ = fmaf(U1[i][1], hB[i], pp_);
                pp_ = fmaf(U1[i][2], hC[i], pp_);
                qq_ = fmaf(U2[i][0], hA[i], qq_);
                qq_ = fmaf(U2[i][1], hB[i], qq_);
                qq_ = fmaf(U2[i][2], hC[i], qq_);
                rr_ = fmaf(U3[i][0], hA[i], rr_);
                rr_ = fmaf(U3[i][1], hB[i], rr_);
                rr_ = fmaf(U3[i][2], hC[i], rr_);
            }
            pp_ = rsum16(pp_);
            qq_ = rsum16(qq_);
            rr_ = rsum16(rr_);
            float P = pp_ + cb1, Q = qq_ + cb2, R = rr_ + cb3;
            float hv = fmaxf(fmaf(P, fast_sigmoid(Q), R), 0.f);
            if ((tid & 15) == 0) dst[w * NODES + node] = f2bf(fmaf(hv, s2, bb2));
        }
#pragma unroll
        for (int i = 0; i < 4; i++) {
            hA[i] = hB[i];
            hB[i] = hC[i];
        }
    }
}

// fc4W [2048][300] f32 -> W4t [304][2048] bf16 (transposed, N-padded)
__global__ __launch_bounds__(256) void k_cvtW4(const float* __restrict__ W,
                                               short* __restrict__ Wt) {
    __shared__ float t[32][33];
    int tx = threadIdx.x & 31, ty = threadIdx.x >> 5;
    int n0 = blockIdx.x * 32, k0 = blockIdx.y * 32;
#pragma unroll
    for (int r = 0; r < 32; r += 8) {
        int k = k0 + r + ty, n = n0 + tx;
        t[r + ty][tx] = (n < FC2_OUT) ? W[(size_t)k * FC2_OUT + n] : 0.f;
    }
    __syncthreads();
#pragma unroll
    for (int r = 0; r < 32; r += 8) {
        int n = n0 + r + ty;
        if (n < NP2) Wt[(size_t)n * FC1_OUT + k0 + tx] = f2bf(t[tx][r + ty]);
    }
}

// ---------------- FC1 MFMA GEMM, B read directly from f32 fcW ----------------
#define KSPL1 8
#define KCH1  (KP1 / KSPL1)  // 800
__global__ __launch_bounds__(256) void k_gemm1f(const short* __restrict__ Ab,
                                                const float* __restrict__ fcW,
                                                float* __restrict__ part) {
    int lane = threadIdx.x & 63, wv = threadIdx.x >> 6;
    int r = lane & 15, kg = lane >> 4;
    int nb = blockIdx.x * 64, sp = blockIdx.y;

    f32x4 acc[2][4] = {};
    const short* a0 = Ab + (size_t)(wv * 32 + r) * KP1;
    const short* a1 = a0 + (size_t)16 * KP1;

    int k0 = sp * KCH1 + kg * 8;
    const float* wp = fcW + (size_t)k0 * FC1_OUT + nb + r;
    bool tailblk = (sp == KSPL1 - 1);

#pragma unroll 1
    for (int s = 0; s < KCH1 / 32; s++, k0 += 32) {
        short8 av0 = *(const short8*)(a0 + k0);
        short8 av1 = *(const short8*)(a1 + k0);
        short8 bv[4];
        if (tailblk && s == KCH1 / 32 - 1) {
#pragma unroll
            for (int f = 0; f < 4; f++)
#pragma unroll
                for (int i = 0; i < 8; i++) {
                    float v = (k0 + i < FC1_IN) ? wp[(size_t)i * FC1_OUT + f * 16] : 0.f;
                    bv[f][i] = f2bf(v);
                }
        } else {
#pragma unroll
            for (int f = 0; f < 4; f++)
#pragma unroll
                for (int i = 0; i < 8; i++)
                    bv[f][i] = f2bf(wp[(size_t)i * FC1_OUT + f * 16]);
        }
        acc[0][0] = __builtin_amdgcn_mfma_f32_16x16x32_bf16(av0, bv[0], acc[0][0], 0, 0, 0);
        acc[1][0] = __builtin_amdgcn_mfma_f32_16x16x32_bf16(av1, bv[0], acc[1][0], 0, 0, 0);
        acc[0][1] = __builtin_amdgcn_mfma_f32_16x16x32_bf16(av0, bv[1], acc[0][1], 0, 0, 0);
        acc[1][1] = __builtin_amdgcn_mfma_f32_16x16x32_bf16(av1, bv[1], acc[1][1], 0, 0, 0);
        acc[0][2] = __builtin_amdgcn_mfma_f32_16x16x32_bf16(av0, bv[2], acc[0][2], 0, 0, 0);
        acc[1][2] = __builtin_amdgcn_mfma_f32_16x16x32_bf16(av1, bv[2], acc[1][2], 0, 0, 0);
        acc[0][3] = __builtin_amdgcn_mfma_f32_16x16x32_bf16(av0, bv[3], acc[0][3], 0, 0, 0);
        acc[1][3] = __builtin_amdgcn_mfma_f32_16x16x32_bf16(av1, bv[3], acc[1][3], 0, 0, 0);
        wp += (size_t)32 * FC1_OUT;
    }

    float* dst = part + (size_t)sp * BATCH * FC1_OUT;
#pragma unroll
    for (int m = 0; m < 2; m++)
#pragma unroll
        for (int f = 0; f < 4; f++)
#pragma unroll
            for (int j = 0; j < 4; j++) {
                int row = wv * 32 + m * 16 + kg * 4 + j;
                int col = nb + f * 16 + r;
                dst[(size_t)row * FC1_OUT + col] = acc[m][f][j];
            }
}

// reduce split-K + bias + ReLU -> bf16 activations for FC2
__global__ __launch_bounds__(256) void k_reduce1(const float* __restrict__ part,
                                                 const float* __restrict__ bias,
                                                 short* __restrict__ Ab2) {
    int idx = blockIdx.x * 256 + threadIdx.x;
    int o = idx & (FC1_OUT - 1);
    float s = bias[o];
#pragma unroll
    for (int sp = 0; sp < KSPL1; sp++) s += part[(size_t)sp * BATCH * FC1_OUT + idx];
    Ab2[idx] = f2bf(fmaxf(s, 0.f));
}

// ---------------- FC2 MFMA GEMM ----------------
#define KSPL2 8
#define KCH2  (FC1_OUT / KSPL2)  // 256
__global__ __launch_bounds__(256) void k_gemm2(const short* __restrict__ Ab,
                                               const short* __restrict__ Wt,
                                               float* __restrict__ part) {
    int lane = threadIdx.x & 63, wv = threadIdx.x >> 6;
    int r = lane & 15, kg = lane >> 4;
    int nb = blockIdx.x * 16, sp = blockIdx.y;

    f32x4 acc[2] = {};
    const short* a0 = Ab + (size_t)(wv * 32 + r) * FC1_OUT;
    const short* a1 = a0 + (size_t)16 * FC1_OUT;
    const short* bp = Wt + (size_t)(nb + r) * FC1_OUT;

    int k0 = sp * KCH2 + kg * 8;
#pragma unroll
    for (int s = 0; s < KCH2 / 32; s++, k0 += 32) {
        short8 av0 = *(const short8*)(a0 + k0);
        short8 av1 = *(const short8*)(a1 + k0);
        short8 bv = *(const short8*)(bp + k0);
        acc[0] = __builtin_amdgcn_mfma_f32_16x16x32_bf16(av0, bv, acc[0], 0, 0, 0);
        acc[1] = __builtin_amdgcn_mfma_f32_16x16x32_bf16(av1, bv, acc[1], 0, 0, 0);
    }

    float* dst = part + (size_t)sp * BATCH * NP2;
#pragma unroll
    for (int m = 0; m < 2; m++)
#pragma unroll
        for (int j = 0; j < 4; j++) {
            int row = wv * 32 + m * 16 + kg * 4 + j;
            int col = nb + r;
            dst[(size_t)row * NP2 + col] = acc[m][j];
        }
}

__global__ __launch_bounds__(256) void k_reduce2(const float* __restrict__ part,
                                                 const float* __restrict__ bias,
                                                 float* __restrict__ out) {
    int idx = blockIdx.x * 256 + threadIdx.x;
    if (idx >= BATCH * NP2) return;
    int b = idx / NP2, o = idx % NP2;
    float s = 0.f;
#pragma unroll
    for (int sp = 0; sp < KSPL2; sp++) s += part[(size_t)sp * BATCH * NP2 + idx];
    if (o < FC2_OUT) out[(size_t)b * FC2_OUT + o] = s + bias[o];
}

extern "C" void kernel_launch(void* const* d_in, const int* in_sizes, int n_in,
                              void* d_out, int out_size, void* d_ws, size_t ws_size,
                              hipStream_t stream) {
    const float* data_x = (const float*)d_in[0];
    const int* ei = (const int*)d_in[1];
    const float* ew = (const float*)d_in[2];
    const float* tc1w1 = (const float*)d_in[3];
    const float* tc1b1 = (const float*)d_in[4];
    const float* tc1w2 = (const float*)d_in[5];
    const float* tc1b2 = (const float*)d_in[6];
    const float* tc1w3 = (const float*)d_in[7];
    const float* tc1b3 = (const float*)d_in[8];
    const float* W0 = (const float*)d_in[9];
    const float* gb0 = (const float*)d_in[10];
    const float* bn0g = (const float*)d_in[11];
    const float* bn0b = (const float*)d_in[12];
    const float* W1 = (const float*)d_in[13];
    const float* gb1 = (const float*)d_in[14];
    const float* bn1g = (const float*)d_in[15];
    const float* bn1b = (const float*)d_in[16];
    const float* tc2w1 = (const float*)d_in[17];
    const float* tc2b1 = (const float*)d_in[18];
    const float* tc2w2 = (const float*)d_in[19];
    const float* tc2b2 = (const float*)d_in[20];
    const float* tc2w3 = (const float*)d_in[21];
    const float* tc2b3 = (const float*)d_in[22];
    const float* bn2g = (const float*)d_in[23];
    const float* bn2b = (const float*)d_in[24];
    const float* fcW = (const float*)d_in[25];
    const float* fcb = (const float*)d_in[26];
    const float* fc4W = (const float*)d_in[27];
    const float* fc4b = (const float*)d_in[28];
    float* out = (float*)d_out;

    char* ws = (char*)d_ws;
    // persistent region: x2 (gfeat source) + Ab (FC1 bf16 activations)
    float* x2 = (float*)(ws + 0);                  // 9,961,472 B
    short* Ab = (short*)(ws + 9961472);            // 1,638,400 B
    const size_t ARENA = 9961472 + 1638400;        // 11,599,872

    // arena A (CSR/GCN phase)
    size_t off = ARENA;
    auto alloc = [&](size_t bytes) -> void* {
        void* p = ws + off;
        off = (off + bytes + 255) & ~(size_t)255;
        return p;
    };
    int* cnt = (int*)alloc((size_t)NSEG * 4);
    int* rowptr = (int*)alloc((size_t)(NSEG + 1) * 4);
    int* cursor = (int*)alloc((size_t)NSEG * 4);
    int* bsum = (int*)alloc((size_t)NB_SCAN * 4);
    int* row_s = (int*)alloc((size_t)NE * 4);
    float* w_s = (float*)alloc((size_t)NE * 4);
    float* dinv = (float*)alloc((size_t)NN * 4);
    unsigned short* h0 = (unsigned short*)alloc((size_t)NN * HID * 2);
    unsigned short* h1 = (unsigned short*)alloc((size_t)NN * HID * 2);

    // x2t overlaps arena A (written by k_xpose AFTER all CSR/GCN consumers done)
    float* x2t = (float*)(ws + ARENA);             // 9,961,472 B

    // arena C (FC phase) — overlaps arena A and x2t, used only after temporal
    off = ARENA;
    float* part1 = (float*)alloc((size_t)KSPL1 * BATCH * FC1_OUT * 4);
    short* Ab2 = (short*)alloc((size_t)BATCH * FC1_OUT * 2);
    short* W4t = (short*)alloc((size_t)NP2 * FC1_OUT * 2);
    float* part2 = (float*)alloc((size_t)KSPL2 * BATCH * NP2 * 4);
    (void)ws_size; (void)in_sizes; (void)n_in; (void)out_size;

    // ---- CSR (source-segmented, 3-kernel scan) ----
    hipMemsetAsync(cnt, 0, (size_t)NSEG * 4, stream);
    k_count<<<(NE + 255) / 256, 256, 0, stream>>>(ei, cnt);
    k_scan1<<<NB_SCAN, 256, 0, stream>>>(cnt, rowptr, bsum);
    k_scan2<<<1, 1024, 0, stream>>>(bsum);
    k_scan3<<<NB_SCAN, 256, 0, stream>>>(rowptr, bsum, cursor);
    k_fill<<<(NE + 255) / 256, 256, 0, stream>>>(ei, ew, cursor, row_s, w_s);
    k_dinv<<<(NN + 255) / 256, 256, 0, stream>>>(rowptr, w_s, dinv);
    k_norm<<<(NN + 255) / 256, 256, 0, stream>>>(rowptr, row_s, dinv, w_s);

    // ---- GCN (bf16 gathered features, 8-deep MLP) ----
    k_mm20<<<NN / 4, 256, 0, stream>>>(data_x, W0, h0);
    k_gatherA<<<NN / 4, 256, 0, stream>>>(rowptr, row_s, w_s, dinv, h0, gb0, bn0g,
                                          bn0b, W1, h1);
    k_gatherB<<<NN / 4, 256, 0, stream>>>(rowptr, row_s, w_s, dinv, h1, gb1, bn1g,
                                          bn1b, x2);

    // ---- transpose x2 for coalesced gfeat ----
    k_xpose<<<NN / 64, 256, 0, stream>>>(x2, x2t);

    // ---- temporal (fused conv1 + concat + conv2 + BN2d) -> bf16 Ab ----
    hipMemsetAsync(Ab, 0, (size_t)BATCH * KP1 * 2, stream);  // zero K-padding
    k_temporal2<<<NN / 16, 256, 0, stream>>>(data_x, x2t, tc1w1, tc1b1, tc1w2, tc1b2,
                                             tc1w3, tc1b3, tc2w1, tc2b1, tc2w2, tc2b2,
                                             tc2w3, tc2b3, bn2g, bn2b, Ab);

    // ---- FC (bf16 MFMA) ----
    {
        dim3 g(FC1_OUT / 64, KSPL1);
        k_gemm1f<<<g, 256, 0, stream>>>(Ab, fcW, part1);
    }
    k_reduce1<<<BATCH * FC1_OUT / 256, 256, 0, stream>>>(part1, fcb, Ab2);
    {
        dim3 g((NP2 + 31) / 32, FC1_OUT / 32);
        k_cvtW4<<<g, 256, 0, stream>>>(fc4W, W4t);
    }
    {
        dim3 g(NP2 / 16, KSPL2);
        k_gemm2<<<g, 256, 0, stream>>>(Ab2, W4t, part2);
    }
    k_reduce2<<<(BATCH * NP2 + 255) / 256, 256, 0, stream>>>(part2, fc4b, out);
}

// Round 7
// 276.209 us; speedup vs baseline: 1.5124x; 1.0028x over previous
//
#include <hip/hip_runtime.h>

#define NODES   304
#define BATCH   128
#define TSTEPS  20
#define HID     64
#define GCNIN   20
#define NN      (BATCH*NODES)      // 38912
#define NE      (NN*16)            // 622592
#define SEG     4
#define SEGSZ   (NN/SEG)           // 9728
#define NSEG    (NN*SEG)           // 155648
#define NB_SCAN (NSEG/256)         // 608
#define FC1_IN  (21*NODES)         // 6384
#define KP1     6400               // FC1_IN padded to /32
#define FC1_OUT 2048
#define FC2_OUT 300
#define NP2     304                // FC2_OUT padded to /16
#define BN_EPS  1e-5f

typedef __attribute__((ext_vector_type(8))) short short8;
typedef __attribute__((ext_vector_type(4))) float f32x4;
typedef __attribute__((ext_vector_type(2))) float f32x2;

static __device__ __forceinline__ short f2bf(float x) {
    unsigned u = __float_as_uint(x);
    unsigned r = (u + 0x7FFF + ((u >> 16) & 1)) >> 16;  // RNE
    return (short)r;
}
static __device__ __forceinline__ float bf2f(unsigned short v) {
    return __uint_as_float((unsigned)v << 16);
}

static __device__ __forceinline__ float fast_sigmoid(float q) {
    return __builtin_amdgcn_rcpf(1.f + __expf(-q));
}

// packed fp32 FMA (VOP3P) — 2x fp32 rate on CDNA4
static __device__ __forceinline__ f32x2 pk_fma(f32x2 a, f32x2 b, f32x2 c) {
    f32x2 d;
    asm("v_pk_fma_f32 %0, %1, %2, %3" : "=v"(d) : "v"(a), "v"(b), "v"(c));
    return d;
}

// DPP row_ror add (VALU pipe, no DS ops)
template <int C>
static __device__ __forceinline__ float dppadd(float v) {
    return v + __int_as_float(
        __builtin_amdgcn_update_dpp(0, __float_as_int(v), C, 0xF, 0xF, false));
}
static __device__ __forceinline__ float rsum16(float v) {
    v = dppadd<0x128>(v);
    v = dppadd<0x124>(v);
    v = dppadd<0x122>(v);
    v = dppadd<0x121>(v);
    return v;
}

// ---------------- CSR build (segmented by source quarter) ----------------
// counts per (col,seg) bucket AND accumulates weighted degree per col
__global__ void k_count(const int* __restrict__ ei, const float* __restrict__ ew,
                        int* __restrict__ cnt, float* __restrict__ degw) {
    int e = blockIdx.x * blockDim.x + threadIdx.x;
    if (e < NE) {
        int c = ei[NE + e];
        atomicAdd(&cnt[c * SEG + ei[e] / SEGSZ], 1);
        atomicAdd(&degw[c], ew[e]);
    }
}

// 3-kernel exclusive scan over cnt[NSEG] -> rowptr/cursor
__global__ __launch_bounds__(256) void k_scan1(const int* __restrict__ cnt,
                                               int* __restrict__ rel,
                                               int* __restrict__ bsum) {
    __shared__ int s[256];
    int tid = threadIdx.x;
    int g = blockIdx.x * 256 + tid;
    int v = cnt[g];
    s[tid] = v;
    __syncthreads();
    for (int d = 1; d < 256; d <<= 1) {
        int t = (tid >= d) ? s[tid - d] : 0;
        __syncthreads();
        s[tid] += t;
        __syncthreads();
    }
    rel[g] = s[tid] - v;  // exclusive within block
    if (tid == 255) bsum[blockIdx.x] = s[255];
}

__global__ __launch_bounds__(1024) void k_scan2(int* __restrict__ bsum) {
    __shared__ int s[1024];
    int tid = threadIdx.x;
    int v = (tid < NB_SCAN) ? bsum[tid] : 0;
    s[tid] = v;
    __syncthreads();
    for (int d = 1; d < 1024; d <<= 1) {
        int t = (tid >= d) ? s[tid - d] : 0;
        __syncthreads();
        s[tid] += t;
        __syncthreads();
    }
    if (tid < NB_SCAN) bsum[tid] = s[tid] - v;  // exclusive block offsets
}

// finalize rowptr/cursor AND compute dinv (elementwise, needs only degw)
__global__ __launch_bounds__(256) void k_scan3(int* __restrict__ rowptr,
                                               const int* __restrict__ bsum,
                                               int* __restrict__ cursor,
                                               const float* __restrict__ degw,
                                               float* __restrict__ dinv) {
    int g = blockIdx.x * 256 + threadIdx.x;
    int val = rowptr[g] + bsum[blockIdx.x];
    rowptr[g] = val;
    cursor[g] = val;
    if (g == 0) rowptr[NSEG] = NE;
    if (g < NN) dinv[g] = rsqrtf(fmaxf(1.f + degw[g], 1e-12f));
}

// fill sorted edge list, writing final norm = dinv[r]*w*dinv[c] directly
__global__ void k_fill(const int* __restrict__ ei, const float* __restrict__ ew,
                       const float* __restrict__ dinv, int* __restrict__ cursor,
                       int* __restrict__ row_s, float* __restrict__ norm_s) {
    int e = blockIdx.x * blockDim.x + threadIdx.x;
    if (e < NE) {
        int c = ei[NE + e];
        int r = ei[e];
        int slot = atomicAdd(&cursor[c * SEG + r / SEGSZ], 1);
        row_s[slot] = r;
        norm_s[slot] = dinv[r] * ew[e] * dinv[c];
    }
}

// ---------------- h0 = data_x @ W0 -> bf16 (4 nodes per 256-thr block) ----------
__global__ __launch_bounds__(256) void k_mm20(const float* __restrict__ X,
                                              const float* __restrict__ W,
                                              unsigned short* __restrict__ H) {
    int wv = threadIdx.x >> 6, f = threadIdx.x & 63;
    int n = blockIdx.x * 4 + wv;
    __shared__ float xs[4][GCNIN];
    if (f < GCNIN) xs[wv][f] = X[(size_t)n * GCNIN + f];
    __syncthreads();
    float acc = 0.f;
#pragma unroll
    for (int k = 0; k < GCNIN; k++) acc = fmaf(xs[wv][k], W[k * HID + f], acc);
    H[(size_t)n * HID + f] = (unsigned short)f2bf(acc);
}

// ------- layer0 gather (LDS-staged edges, 16-deep) + BN + ReLU + matvec @W1 -------
__global__ __launch_bounds__(256) void k_gatherA(const int* __restrict__ rowptr,
                                                 const int* __restrict__ row_s,
                                                 const float* __restrict__ norm_s,
                                                 const float* __restrict__ dinv,
                                                 const unsigned short* __restrict__ H0,
                                                 const float* __restrict__ gb,
                                                 const float* __restrict__ bng,
                                                 const float* __restrict__ bnb,
                                                 const float* __restrict__ W1,
                                                 unsigned short* __restrict__ H1) {
    int wv = threadIdx.x >> 6, f = threadIdx.x & 63;
    int c = blockIdx.x * 4 + wv;
    __shared__ int sIdx[4][64];
    __shared__ float sWt[4][64];
    __shared__ float xs[4][HID];

    int j0 = rowptr[c * SEG], j1 = rowptr[c * SEG + SEG];
    int deg = j1 - j0;
    int dcap = deg < 64 ? deg : 64;
    if (f < dcap) {
        sIdx[wv][f] = row_s[j0 + f];
        sWt[wv][f] = norm_s[j0 + f];
    }
    __syncthreads();

    float dc = dinv[c];
    float acc = bf2f(H0[(size_t)c * HID + f]) * dc * dc;  // self loop
    for (int base = 0; base < dcap; base += 16) {
        int idx[16];
        float w[16];
#pragma unroll
        for (int i = 0; i < 16; i++) {
            int l = (base + i < dcap) ? base + i : dcap - 1;
            idx[i] = sIdx[wv][l];
            w[i] = (base + i < dcap) ? sWt[wv][l] : 0.f;
        }
        float v[16];
#pragma unroll
        for (int i = 0; i < 16; i++) v[i] = bf2f(H0[(size_t)idx[i] * HID + f]);
#pragma unroll
        for (int i = 0; i < 16; i++) acc = fmaf(v[i], w[i], acc);
    }
    for (int j = j0 + 64; j < j1; j++)  // astronomically rare overflow
        acc += bf2f(H0[(size_t)row_s[j] * HID + f]) * norm_s[j];

    float scale = bng[f] * rsqrtf(1.f + BN_EPS);
    float y = fmaxf(fmaf(acc + gb[f], scale, bnb[f]), 0.f);  // x1[c][f]

    xs[wv][f] = y;
    __syncthreads();
    float h = 0.f;
#pragma unroll
    for (int k4 = 0; k4 < HID / 4; k4++) {
        float4 xv = *(const float4*)&xs[wv][k4 * 4];
        h = fmaf(xv.x, W1[(k4 * 4 + 0) * HID + f], h);
        h = fmaf(xv.y, W1[(k4 * 4 + 1) * HID + f], h);
        h = fmaf(xv.z, W1[(k4 * 4 + 2) * HID + f], h);
        h = fmaf(xv.w, W1[(k4 * 4 + 3) * HID + f], h);
    }
    H1[(size_t)c * HID + f] = (unsigned short)f2bf(h);
}

// -------- layer1 gather (LDS-staged edges, 16-deep) + BN + ReLU -> x2 f32 --------
__global__ __launch_bounds__(256) void k_gatherB(const int* __restrict__ rowptr,
                                                 const int* __restrict__ row_s,
                                                 const float* __restrict__ norm_s,
                                                 const float* __restrict__ dinv,
                                                 const unsigned short* __restrict__ H,
                                                 const float* __restrict__ gb,
                                                 const float* __restrict__ bng,
                                                 const float* __restrict__ bnb,
                                                 float* __restrict__ XO) {
    int wv = threadIdx.x >> 6, f = threadIdx.x & 63;
    int c = blockIdx.x * 4 + wv;
    __shared__ int sIdx[4][64];
    __shared__ float sWt[4][64];

    int j0 = rowptr[c * SEG], j1 = rowptr[c * SEG + SEG];
    int deg = j1 - j0;
    int dcap = deg < 64 ? deg : 64;
    if (f < dcap) {
        sIdx[wv][f] = row_s[j0 + f];
        sWt[wv][f] = norm_s[j0 + f];
    }
    __syncthreads();

    float dc = dinv[c];
    float acc = bf2f(H[(size_t)c * HID + f]) * dc * dc;
    for (int base = 0; base < dcap; base += 16) {
        int idx[16];
        float w[16];
#pragma unroll
        for (int i = 0; i < 16; i++) {
            int l = (base + i < dcap) ? base + i : dcap - 1;
            idx[i] = sIdx[wv][l];
            w[i] = (base + i < dcap) ? sWt[wv][l] : 0.f;
        }
        float v[16];
#pragma unroll
        for (int i = 0; i < 16; i++) v[i] = bf2f(H[(size_t)idx[i] * HID + f]);
#pragma unroll
        for (int i = 0; i < 16; i++) acc = fmaf(v[i], w[i], acc);
    }
    for (int j = j0 + 64; j < j1; j++)
        acc += bf2f(H[(size_t)row_s[j] * HID + f]) * norm_s[j];

    float scale = bng[f] * rsqrtf(1.f + BN_EPS);
    XO[(size_t)c * HID + f] = fmaxf(fmaf(acc + gb[f], scale, bnb[f]), 0.f);
}

// ---------------- x2 [38912][64] -> x2t [64][38912] ----------------
__global__ __launch_bounds__(256) void k_xpose(const float* __restrict__ x2,
                                               float* __restrict__ x2t) {
    __shared__ float tile[64][65];
    int n0 = blockIdx.x * 64;
    for (int i = threadIdx.x; i < 4096; i += 256) {
        int r = i >> 6, h = i & 63;
        tile[r][h] = x2[(size_t)(n0 + r) * 64 + h];
    }
    __syncthreads();
    for (int i = threadIdx.x; i < 4096; i += 256) {
        int h = i >> 6, c = i & 63;
        x2t[(size_t)h * NN + n0 + c] = tile[c][h];
    }
}

// ---------------- fused temporal: packed-fp32, 16 pairs/block, 4 ch/lane ----
// writes bf16 directly into padded GEMM A buffer: Ab[b][t2*304+node]
__global__ __launch_bounds__(256) void k_temporal2(
    const float* __restrict__ data_x, const float* __restrict__ x2t,
    const float* __restrict__ w1, const float* __restrict__ b1,
    const float* __restrict__ w2, const float* __restrict__ b2,
    const float* __restrict__ w3, const float* __restrict__ b3,
    const float* __restrict__ v1, const float* __restrict__ vb1,
    const float* __restrict__ v2, const float* __restrict__ vb2,
    const float* __restrict__ v3, const float* __restrict__ vb3,
    const float* __restrict__ bn2g, const float* __restrict__ bn2b,
    short* __restrict__ Ab) {
    int bn0 = blockIdx.x * 16;
    int b = bn0 / NODES, node0 = bn0 % NODES;  // 304%16==0: never straddles b
    int tid = threadIdx.x;
    int p = tid >> 4;            // pair 0..15
    int c0 = (tid & 15) << 2;    // channel base (4 channels/lane, 2 f32x2 pairs)
    int node = node0 + p;

    __shared__ float xs[16][22];
    for (int i = tid; i < 320; i += 256) {
        int t = i >> 4, pp = i & 15;
        xs[pp][t + 1] = data_x[b * (TSTEPS * NODES) + t * NODES + node0 + pp];
    }
    if (tid < 16) { xs[tid][0] = 0.f; xs[tid][21] = 0.f; }

    // packed weights: channel-pair cp covers channels (c0+2cp, c0+2cp+1)
    f32x2 A1p[2][3], A2p[2][3], A3p[2][3], B1p[2], B2p[2], B3p[2];
    f32x2 U1p[2][3], U2p[2][3], U3p[2][3];
#pragma unroll
    for (int cp = 0; cp < 2; cp++) {
        int ca = c0 + 2 * cp, cb = ca + 1;
#pragma unroll
        for (int k = 0; k < 3; k++) {
            A1p[cp][k][0] = w1[ca * 3 + k]; A1p[cp][k][1] = w1[cb * 3 + k];
            A2p[cp][k][0] = w2[ca * 3 + k]; A2p[cp][k][1] = w2[cb * 3 + k];
            A3p[cp][k][0] = w3[ca * 3 + k]; A3p[cp][k][1] = w3[cb * 3 + k];
            U1p[cp][k][0] = v1[ca * 3 + k]; U1p[cp][k][1] = v1[cb * 3 + k];
            U2p[cp][k][0] = v2[ca * 3 + k]; U2p[cp][k][1] = v2[cb * 3 + k];
            U3p[cp][k][0] = v3[ca * 3 + k]; U3p[cp][k][1] = v3[cb * 3 + k];
        }
        B1p[cp][0] = b1[ca]; B1p[cp][1] = b1[cb];
        B2p[cp][0] = b2[ca]; B2p[cp][1] = b2[cb];
        B3p[cp][0] = b3[ca]; B3p[cp][1] = b3[cb];
    }
    float cb1 = vb1[0], cb2 = vb2[0], cb3 = vb3[0];
    float s2 = bn2g[node] * rsqrtf(1.f + BN_EPS);
    float bb2 = bn2b[node];
    short* dst = Ab + (size_t)b * KP1;

    __syncthreads();

    f32x2 hA2[2] = {}, hB2[2] = {}, hC2[2];
    float xr0 = xs[p][0], xr1 = xs[p][1];

#pragma unroll
    for (int j = 0; j <= 21; j++) {
        if (j < 20) {
            float xr2 = xs[p][j + 2];
            f32x2 x0d, x1d, x2d;
            x0d[0] = xr0; x0d[1] = xr0;
            x1d[0] = xr1; x1d[1] = xr1;
            x2d[0] = xr2; x2d[1] = xr2;
#pragma unroll
            for (int cp = 0; cp < 2; cp++) {
                f32x2 pv = pk_fma(A1p[cp][2], x2d,
                            pk_fma(A1p[cp][1], x1d, pk_fma(A1p[cp][0], x0d, B1p[cp])));
                f32x2 qv = pk_fma(A2p[cp][2], x2d,
                            pk_fma(A2p[cp][1], x1d, pk_fma(A2p[cp][0], x0d, B2p[cp])));
                f32x2 rv = pk_fma(A3p[cp][2], x2d,
                            pk_fma(A3p[cp][1], x1d, pk_fma(A3p[cp][0], x0d, B3p[cp])));
                hC2[cp][0] = fmaxf(fmaf(pv[0], fast_sigmoid(qv[0]), rv[0]), 0.f);
                hC2[cp][1] = fmaxf(fmaf(pv[1], fast_sigmoid(qv[1]), rv[1]), 0.f);
            }
            xr0 = xr1;
            xr1 = xr2;
        } else if (j == 20) {
            const float4 gv = *(const float4*)(x2t + (size_t)(b >> 1) * NN +
                                               (b & 1) * (NODES * HID) + node * HID + c0);
            hC2[0][0] = fmaxf(gv.x, 0.f);
            hC2[0][1] = fmaxf(gv.y, 0.f);
            hC2[1][0] = fmaxf(gv.z, 0.f);
            hC2[1][1] = fmaxf(gv.w, 0.f);
        } else {
            hC2[0][0] = 0.f; hC2[0][1] = 0.f;
            hC2[1][0] = 0.f; hC2[1][1] = 0.f;
        }
        if (j >= 1) {
            int w = j - 1;
            f32x2 pa, qa, ra;
            pa[0] = 0.f; pa[1] = 0.f;
            qa[0] = 0.f; qa[1] = 0.f;
            ra[0] = 0.f; ra[1] = 0.f;
#pragma unroll
            for (int cp = 0; cp < 2; cp++) {
                pa = pk_fma(U1p[cp][0], hA2[cp], pa);
                pa = pk_fma(U1p[cp][1], hB2[cp], pa);
                pa = pk_fma(U1p[cp][2], hC2[cp], pa);
                qa = pk_fma(U2p[cp][0], hA2[cp], qa);
                qa = pk_fma(U2p[cp][1], hB2[cp], qa);
                qa = pk_fma(U2p[cp][2], hC2[cp], qa);
                ra = pk_fma(U3p[cp][0], hA2[cp], ra);
                ra = pk_fma(U3p[cp][1], hB2[cp], ra);
                ra = pk_fma(U3p[cp][2], hC2[cp], ra);
            }
            float pp_ = rsum16(pa[0] + pa[1]);
            float qq_ = rsum16(qa[0] + qa[1]);
            float rr_ = rsum16(ra[0] + ra[1]);
            float P = pp_ + cb1, Q = qq_ + cb2, R = rr_ + cb3;
            float hv = fmaxf(fmaf(P, fast_sigmoid(Q), R), 0.f);
            if ((tid & 15) == 0) dst[w * NODES + node] = f2bf(fmaf(hv, s2, bb2));
        }
        hA2[0] = hB2[0]; hA2[1] = hB2[1];
        hB2[0] = hC2[0]; hB2[1] = hC2[1];
    }
}

// fc4W [2048][300] f32 -> W4t [304][2048] bf16 (transposed, N-padded)
__global__ __launch_bounds__(256) void k_cvtW4(const float* __restrict__ W,
                                               short* __restrict__ Wt) {
    __shared__ float t[32][33];
    int tx = threadIdx.x & 31, ty = threadIdx.x >> 5;
    int n0 = blockIdx.x * 32, k0 = blockIdx.y * 32;
#pragma unroll
    for (int r = 0; r < 32; r += 8) {
        int k = k0 + r + ty, n = n0 + tx;
        t[r + ty][tx] = (n < FC2_OUT) ? W[(size_t)k * FC2_OUT + n] : 0.f;
    }
    __syncthreads();
#pragma unroll
    for (int r = 0; r < 32; r += 8) {
        int n = n0 + r + ty;
        if (n < NP2) Wt[(size_t)n * FC1_OUT + k0 + tx] = f2bf(t[tx][r + ty]);
    }
}

// ---------------- FC1 MFMA GEMM, B read directly from f32 fcW ----------------
#define KSPL1 8
#define KCH1  (KP1 / KSPL1)  // 800
__global__ __launch_bounds__(256) void k_gemm1f(const short* __restrict__ Ab,
                                                const float* __restrict__ fcW,
                                                float* __restrict__ part) {
    int lane = threadIdx.x & 63, wv = threadIdx.x >> 6;
    int r = lane & 15, kg = lane >> 4;
    int nb = blockIdx.x * 64, sp = blockIdx.y;

    f32x4 acc[2][4] = {};
    const short* a0 = Ab + (size_t)(wv * 32 + r) * KP1;
    const short* a1 = a0 + (size_t)16 * KP1;

    int k0 = sp * KCH1 + kg * 8;
    const float* wp = fcW + (size_t)k0 * FC1_OUT + nb + r;
    bool tailblk = (sp == KSPL1 - 1);

#pragma unroll 1
    for (int s = 0; s < KCH1 / 32; s++, k0 += 32) {
        short8 av0 = *(const short8*)(a0 + k0);
        short8 av1 = *(const short8*)(a1 + k0);
        short8 bv[4];
        if (tailblk && s == KCH1 / 32 - 1) {
#pragma unroll
            for (int f = 0; f < 4; f++)
#pragma unroll
                for (int i = 0; i < 8; i++) {
                    float v = (k0 + i < FC1_IN) ? wp[(size_t)i * FC1_OUT + f * 16] : 0.f;
                    bv[f][i] = f2bf(v);
                }
        } else {
#pragma unroll
            for (int f = 0; f < 4; f++)
#pragma unroll
                for (int i = 0; i < 8; i++)
                    bv[f][i] = f2bf(wp[(size_t)i * FC1_OUT + f * 16]);
        }
        acc[0][0] = __builtin_amdgcn_mfma_f32_16x16x32_bf16(av0, bv[0], acc[0][0], 0, 0, 0);
        acc[1][0] = __builtin_amdgcn_mfma_f32_16x16x32_bf16(av1, bv[0], acc[1][0], 0, 0, 0);
        acc[0][1] = __builtin_amdgcn_mfma_f32_16x16x32_bf16(av0, bv[1], acc[0][1], 0, 0, 0);
        acc[1][1] = __builtin_amdgcn_mfma_f32_16x16x32_bf16(av1, bv[1], acc[1][1], 0, 0, 0);
        acc[0][2] = __builtin_amdgcn_mfma_f32_16x16x32_bf16(av0, bv[2], acc[0][2], 0, 0, 0);
        acc[1][2] = __builtin_amdgcn_mfma_f32_16x16x32_bf16(av1, bv[2], acc[1][2], 0, 0, 0);
        acc[0][3] = __builtin_amdgcn_mfma_f32_16x16x32_bf16(av0, bv[3], acc[0][3], 0, 0, 0);
        acc[1][3] = __builtin_amdgcn_mfma_f32_16x16x32_bf16(av1, bv[3], acc[1][3], 0, 0, 0);
        wp += (size_t)32 * FC1_OUT;
    }

    float* dst = part + (size_t)sp * BATCH * FC1_OUT;
#pragma unroll
    for (int m = 0; m < 2; m++)
#pragma unroll
        for (int f = 0; f < 4; f++)
#pragma unroll
            for (int j = 0; j < 4; j++) {
                int row = wv * 32 + m * 16 + kg * 4 + j;
                int col = nb + f * 16 + r;
                dst[(size_t)row * FC1_OUT + col] = acc[m][f][j];
            }
}

// reduce split-K + bias + ReLU -> bf16 activations for FC2
__global__ __launch_bounds__(256) void k_reduce1(const float* __restrict__ part,
                                                 const float* __restrict__ bias,
                                                 short* __restrict__ Ab2) {
    int idx = blockIdx.x * 256 + threadIdx.x;
    int o = idx & (FC1_OUT - 1);
    float s = bias[o];
#pragma unroll
    for (int sp = 0; sp < KSPL1; sp++) s += part[(size_t)sp * BATCH * FC1_OUT + idx];
    Ab2[idx] = f2bf(fmaxf(s, 0.f));
}

// ---------------- FC2 MFMA GEMM ----------------
#define KSPL2 8
#define KCH2  (FC1_OUT / KSPL2)  // 256
__global__ __launch_bounds__(256) void k_gemm2(const short* __restrict__ Ab,
                                               const short* __restrict__ Wt,
                                               float* __restrict__ part) {
    int lane = threadIdx.x & 63, wv = threadIdx.x >> 6;
    int r = lane & 15, kg = lane >> 4;
    int nb = blockIdx.x * 16, sp = blockIdx.y;

    f32x4 acc[2] = {};
    const short* a0 = Ab + (size_t)(wv * 32 + r) * FC1_OUT;
    const short* a1 = a0 + (size_t)16 * FC1_OUT;
    const short* bp = Wt + (size_t)(nb + r) * FC1_OUT;

    int k0 = sp * KCH2 + kg * 8;
#pragma unroll
    for (int s = 0; s < KCH2 / 32; s++, k0 += 32) {
        short8 av0 = *(const short8*)(a0 + k0);
        short8 av1 = *(const short8*)(a1 + k0);
        short8 bv = *(const short8*)(bp + k0);
        acc[0] = __builtin_amdgcn_mfma_f32_16x16x32_bf16(av0, bv, acc[0], 0, 0, 0);
        acc[1] = __builtin_amdgcn_mfma_f32_16x16x32_bf16(av1, bv, acc[1], 0, 0, 0);
    }

    float* dst = part + (size_t)sp * BATCH * NP2;
#pragma unroll
    for (int m = 0; m < 2; m++)
#pragma unroll
        for (int j = 0; j < 4; j++) {
            int row = wv * 32 + m * 16 + kg * 4 + j;
            int col = nb + r;
            dst[(size_t)row * NP2 + col] = acc[m][j];
        }
}

__global__ __launch_bounds__(256) void k_reduce2(const float* __restrict__ part,
                                                 const float* __restrict__ bias,
                                                 float* __restrict__ out) {
    int idx = blockIdx.x * 256 + threadIdx.x;
    if (idx >= BATCH * NP2) return;
    int b = idx / NP2, o = idx % NP2;
    float s = 0.f;
#pragma unroll
    for (int sp = 0; sp < KSPL2; sp++) s += part[(size_t)sp * BATCH * NP2 + idx];
    if (o < FC2_OUT) out[(size_t)b * FC2_OUT + o] = s + bias[o];
}

extern "C" void kernel_launch(void* const* d_in, const int* in_sizes, int n_in,
                              void* d_out, int out_size, void* d_ws, size_t ws_size,
                              hipStream_t stream) {
    const float* data_x = (const float*)d_in[0];
    const int* ei = (const int*)d_in[1];
    const float* ew = (const float*)d_in[2];
    const float* tc1w1 = (const float*)d_in[3];
    const float* tc1b1 = (const float*)d_in[4];
    const float* tc1w2 = (const float*)d_in[5];
    const float* tc1b2 = (const float*)d_in[6];
    const float* tc1w3 = (const float*)d_in[7];
    const float* tc1b3 = (const float*)d_in[8];
    const float* W0 = (const float*)d_in[9];
    const float* gb0 = (const float*)d_in[10];
    const float* bn0g = (const float*)d_in[11];
    const float* bn0b = (const float*)d_in[12];
    const float* W1 = (const float*)d_in[13];
    const float* gb1 = (const float*)d_in[14];
    const float* bn1g = (const float*)d_in[15];
    const float* bn1b = (const float*)d_in[16];
    const float* tc2w1 = (const float*)d_in[17];
    const float* tc2b1 = (const float*)d_in[18];
    const float* tc2w2 = (const float*)d_in[19];
    const float* tc2b2 = (const float*)d_in[20];
    const float* tc2w3 = (const float*)d_in[21];
    const float* tc2b3 = (const float*)d_in[22];
    const float* bn2g = (const float*)d_in[23];
    const float* bn2b = (const float*)d_in[24];
    const float* fcW = (const float*)d_in[25];
    const float* fcb = (const float*)d_in[26];
    const float* fc4W = (const float*)d_in[27];
    const float* fc4b = (const float*)d_in[28];
    float* out = (float*)d_out;

    char* ws = (char*)d_ws;
    // persistent region: x2 (gfeat source) + Ab (FC1 bf16 activations)
    float* x2 = (float*)(ws + 0);                  // 9,961,472 B
    short* Ab = (short*)(ws + 9961472);            // 1,638,400 B
    const size_t ARENA = 9961472 + 1638400;        // 11,599,872

    // arena A (CSR/GCN phase)
    size_t off = ARENA;
    auto alloc = [&](size_t bytes) -> void* {
        void* p = ws + off;
        off = (off + bytes + 255) & ~(size_t)255;
        return p;
    };
    int* cnt = (int*)alloc((size_t)(NSEG + NN) * 4);  // cnt[NSEG] ++ degw[NN]
    float* degw = (float*)(cnt + NSEG);
    int* rowptr = (int*)alloc((size_t)(NSEG + 1) * 4);
    int* cursor = (int*)alloc((size_t)NSEG * 4);
    int* bsum = (int*)alloc((size_t)NB_SCAN * 4);
    int* row_s = (int*)alloc((size_t)NE * 4);
    float* norm_s = (float*)alloc((size_t)NE * 4);
    float* dinv = (float*)alloc((size_t)NN * 4);
    unsigned short* h0 = (unsigned short*)alloc((size_t)NN * HID * 2);
    unsigned short* h1 = (unsigned short*)alloc((size_t)NN * HID * 2);

    // x2t overlaps arena A (written by k_xpose AFTER all CSR/GCN consumers done)
    float* x2t = (float*)(ws + ARENA);             // 9,961,472 B

    // arena C (FC phase) — overlaps arena A and x2t, used only after temporal
    off = ARENA;
    float* part1 = (float*)alloc((size_t)KSPL1 * BATCH * FC1_OUT * 4);
    short* Ab2 = (short*)alloc((size_t)BATCH * FC1_OUT * 2);
    short* W4t = (short*)alloc((size_t)NP2 * FC1_OUT * 2);
    float* part2 = (float*)alloc((size_t)KSPL2 * BATCH * NP2 * 4);
    (void)ws_size; (void)in_sizes; (void)n_in; (void)out_size;

    // ---- CSR (source-segmented; dinv fused into scan3; norm fused into fill) ----
    hipMemsetAsync(cnt, 0, (size_t)(NSEG + NN) * 4, stream);
    k_count<<<(NE + 255) / 256, 256, 0, stream>>>(ei, ew, cnt, degw);
    k_scan1<<<NB_SCAN, 256, 0, stream>>>(cnt, rowptr, bsum);
    k_scan2<<<1, 1024, 0, stream>>>(bsum);
    k_scan3<<<NB_SCAN, 256, 0, stream>>>(rowptr, bsum, cursor, degw, dinv);
    k_fill<<<(NE + 255) / 256, 256, 0, stream>>>(ei, ew, dinv, cursor, row_s, norm_s);

    // ---- GCN (bf16 gathered features, LDS-staged 16-deep) ----
    k_mm20<<<NN / 4, 256, 0, stream>>>(data_x, W0, h0);
    k_gatherA<<<NN / 4, 256, 0, stream>>>(rowptr, row_s, norm_s, dinv, h0, gb0, bn0g,
                                          bn0b, W1, h1);
    k_gatherB<<<NN / 4, 256, 0, stream>>>(rowptr, row_s, norm_s, dinv, h1, gb1, bn1g,
                                          bn1b, x2);

    // ---- transpose x2 for coalesced gfeat ----
    k_xpose<<<NN / 64, 256, 0, stream>>>(x2, x2t);

    // ---- temporal (fused conv1 + concat + conv2 + BN2d, packed fp32) -> bf16 Ab ----
    hipMemsetAsync(Ab, 0, (size_t)BATCH * KP1 * 2, stream);  // zero K-padding
    k_temporal2<<<NN / 16, 256, 0, stream>>>(data_x, x2t, tc1w1, tc1b1, tc1w2, tc1b2,
                                             tc1w3, tc1b3, tc2w1, tc2b1, tc2w2, tc2b2,
                                             tc2w3, tc2b3, bn2g, bn2b, Ab);

    // ---- FC (bf16 MFMA) ----
    {
        dim3 g(FC1_OUT / 64, KSPL1);
        k_gemm1f<<<g, 256, 0, stream>>>(Ab, fcW, part1);
    }
    k_reduce1<<<BATCH * FC1_OUT / 256, 256, 0, stream>>>(part1, fcb, Ab2);
    {
        dim3 g((NP2 + 31) / 32, FC1_OUT / 32);
        k_cvtW4<<<g, 256, 0, stream>>>(fc4W, W4t);
    }
    {
        dim3 g(NP2 / 16, KSPL2);
        k_gemm2<<<g, 256, 0, stream>>>(Ab2, W4t, part2);
    }
    k_reduce2<<<(BATCH * NP2 + 255) / 256, 256, 0, stream>>>(part2, fc4b, out);
}

// Round 8
// 214.681 us; speedup vs baseline: 1.9459x; 1.2866x over previous
//
#include <hip/hip_runtime.h>

#define NODES   304
#define BATCH   128
#define TSTEPS  20
#define HID     64
#define GCNIN   20
#define NN      (BATCH*NODES)      // 38912
#define NE      (NN*16)            // 622592
#define SEGSZ   (NN/4)             // 9728 (row-quarter for L2 phasing)
#define BCAP    64                 // bucket capacity per col (P(overflow)~2e-18)
#define FC1_IN  (21*NODES)         // 6384
#define KP1     6400               // FC1_IN padded to /32
#define FC1_OUT 2048
#define FC2_OUT 300
#define NP2     304                // FC2_OUT padded to /16
#define BN_EPS  1e-5f

typedef __attribute__((ext_vector_type(8))) short short8;
typedef __attribute__((ext_vector_type(4))) float f32x4;
typedef __attribute__((ext_vector_type(2))) float f32x2;

static __device__ __forceinline__ short f2bf(float x) {
    unsigned u = __float_as_uint(x);
    unsigned r = (u + 0x7FFF + ((u >> 16) & 1)) >> 16;  // RNE
    return (short)r;
}
static __device__ __forceinline__ float bf2f(unsigned short v) {
    return __uint_as_float((unsigned)v << 16);
}

static __device__ __forceinline__ float fast_sigmoid(float q) {
    return __builtin_amdgcn_rcpf(1.f + __expf(-q));
}

// packed fp32 FMA (VOP3P) — 2x fp32 rate on CDNA4
static __device__ __forceinline__ f32x2 pk_fma(f32x2 a, f32x2 b, f32x2 c) {
    f32x2 d;
    asm("v_pk_fma_f32 %0, %1, %2, %3" : "=v"(d) : "v"(a), "v"(b), "v"(c));
    return d;
}

// DPP row_ror add (VALU pipe, no DS ops)
template <int C>
static __device__ __forceinline__ float dppadd(float v) {
    return v + __int_as_float(
        __builtin_amdgcn_update_dpp(0, __float_as_int(v), C, 0xF, 0xF, false));
}
static __device__ __forceinline__ float rsum16(float v) {
    v = dppadd<0x128>(v);
    v = dppadd<0x124>(v);
    v = dppadd<0x122>(v);
    v = dppadd<0x121>(v);
    return v;
}

// ---------------- bucketed edge build: ONE global atomic per edge ----------------
__global__ void k_bucket(const int* __restrict__ ei, const float* __restrict__ ew,
                         int* __restrict__ cnt, int2* __restrict__ bucket) {
    int e = blockIdx.x * blockDim.x + threadIdx.x;
    if (e < NE) {
        int c = ei[NE + e];
        int slot = atomicAdd(&cnt[c], 1);
        if (slot < BCAP) {
            int2 v;
            v.x = ei[e];
            v.y = __float_as_int(ew[e]);
            bucket[((size_t)c << 6) + slot] = v;
        }
    }
}

// dinv[c] = rsqrt(1 + sum_w) from the col's contiguous bucket (no atomics)
__global__ __launch_bounds__(256) void k_dinv2(const int* __restrict__ cnt,
                                               const int2* __restrict__ bucket,
                                               float* __restrict__ dinv) {
    int c = blockIdx.x * 256 + threadIdx.x;
    if (c >= NN) return;
    int n = cnt[c];
    if (n > BCAP) n = BCAP;
    const int2* bp = bucket + ((size_t)c << 6);
    float s = 1.f;  // self loop
    for (int i = 0; i < n; i += 8) {
        float v[8];
#pragma unroll
        for (int k = 0; k < 8; k++) {
            int l = (i + k < n) ? i + k : n - 1;
            v[k] = (i + k < n) ? __int_as_float(bp[l].y) : 0.f;
        }
#pragma unroll
        for (int k = 0; k < 8; k++) s += v[k];
    }
    dinv[c] = rsqrtf(fmaxf(s, 1e-12f));
}

// ---------------- h0' = dinv * (data_x @ W0) -> bf16 ----------------
__global__ __launch_bounds__(256) void k_mm20(const float* __restrict__ X,
                                              const float* __restrict__ W,
                                              const float* __restrict__ dinv,
                                              unsigned short* __restrict__ H) {
    int wv = threadIdx.x >> 6, f = threadIdx.x & 63;
    int n = blockIdx.x * 4 + wv;
    __shared__ float xs[4][GCNIN];
    if (f < GCNIN) xs[wv][f] = X[(size_t)n * GCNIN + f];
    __syncthreads();
    float acc = 0.f;
#pragma unroll
    for (int k = 0; k < GCNIN; k++) acc = fmaf(xs[wv][k], W[k * HID + f], acc);
    H[(size_t)n * HID + f] = (unsigned short)f2bf(acc * dinv[n]);
}

// ballot-partition the wave's staged edges by row-quarter (restores L2 phasing)
static __device__ __forceinline__ void stage_partition(
    const int* __restrict__ cnt, const int2* __restrict__ bucket, int c, int f,
    int wv, int (*sIdx)[BCAP], float (*sWt)[BCAP], int& dcap) {
    int deg = cnt[c];
    dcap = deg < BCAP ? deg : BCAP;
    bool valid = f < dcap;
    int row = 0;
    float w = 0.f;
    if (valid) {
        int2 e = bucket[((size_t)c << 6) + f];
        row = e.x;
        w = __int_as_float(e.y);
    }
    int q = (row >= SEGSZ) + (row >= 2 * SEGSZ) + (row >= 3 * SEGSZ);
    unsigned long long b0 = __ballot(valid && q == 0);
    unsigned long long b1 = __ballot(valid && q == 1);
    unsigned long long b2 = __ballot(valid && q == 2);
    unsigned long long b3 = __ballot(valid && q == 3);
    unsigned long long lmask = (1ULL << f) - 1;
    int pos = 0;
    if (q > 0) pos += __popcll(b0);
    if (q > 1) pos += __popcll(b1);
    if (q > 2) pos += __popcll(b2);
    unsigned long long mybal = (q == 0) ? b0 : (q == 1) ? b1 : (q == 2) ? b2 : b3;
    pos += __popcll(mybal & lmask);
    if (valid) {
        sIdx[wv][pos] = row;
        sWt[wv][pos] = w;
    }
}

// ------- layer0 gather (pre-scaled bf16 feats) + BN + ReLU + matvec @W1 -------
__global__ __launch_bounds__(256) void k_gatherA(const int* __restrict__ cnt,
                                                 const int2* __restrict__ bucket,
                                                 const float* __restrict__ dinv,
                                                 const unsigned short* __restrict__ H0,
                                                 const float* __restrict__ gb,
                                                 const float* __restrict__ bng,
                                                 const float* __restrict__ bnb,
                                                 const float* __restrict__ W1,
                                                 unsigned short* __restrict__ H1) {
    int wv = threadIdx.x >> 6, f = threadIdx.x & 63;
    int c = blockIdx.x * 4 + wv;
    __shared__ int sIdx[4][BCAP];
    __shared__ float sWt[4][BCAP];
    __shared__ float xs[4][HID];

    int dcap;
    stage_partition(cnt, bucket, c, f, wv, sIdx, sWt, dcap);
    __syncthreads();

    float dc = dinv[c];
    float acc = bf2f(H0[(size_t)c * HID + f]);  // self loop (pre-scaled)
    for (int base = 0; base < dcap; base += 16) {
        int idx[16];
        float w[16];
#pragma unroll
        for (int i = 0; i < 16; i++) {
            int l = (base + i < dcap) ? base + i : dcap - 1;
            idx[i] = sIdx[wv][l];
            w[i] = (base + i < dcap) ? sWt[wv][l] : 0.f;
        }
        float v[16];
#pragma unroll
        for (int i = 0; i < 16; i++) v[i] = bf2f(H0[(size_t)idx[i] * HID + f]);
#pragma unroll
        for (int i = 0; i < 16; i++) acc = fmaf(v[i], w[i], acc);
    }
    float scale = bng[f] * rsqrtf(1.f + BN_EPS);
    float y = fmaxf(fmaf(acc * dc + gb[f], scale, bnb[f]), 0.f);  // x1[c][f]

    xs[wv][f] = y;
    __syncthreads();
    float h = 0.f;
#pragma unroll
    for (int k4 = 0; k4 < HID / 4; k4++) {
        float4 xv = *(const float4*)&xs[wv][k4 * 4];
        h = fmaf(xv.x, W1[(k4 * 4 + 0) * HID + f], h);
        h = fmaf(xv.y, W1[(k4 * 4 + 1) * HID + f], h);
        h = fmaf(xv.z, W1[(k4 * 4 + 2) * HID + f], h);
        h = fmaf(xv.w, W1[(k4 * 4 + 3) * HID + f], h);
    }
    H1[(size_t)c * HID + f] = (unsigned short)f2bf(h * dc);  // pre-scaled
}

// -------- layer1 gather (pre-scaled bf16 feats) + BN + ReLU -> x2 f32 --------
__global__ __launch_bounds__(256) void k_gatherB(const int* __restrict__ cnt,
                                                 const int2* __restrict__ bucket,
                                                 const float* __restrict__ dinv,
                                                 const unsigned short* __restrict__ H,
                                                 const float* __restrict__ gb,
                                                 const float* __restrict__ bng,
                                                 const float* __restrict__ bnb,
                                                 float* __restrict__ XO) {
    int wv = threadIdx.x >> 6, f = threadIdx.x & 63;
    int c = blockIdx.x * 4 + wv;
    __shared__ int sIdx[4][BCAP];
    __shared__ float sWt[4][BCAP];

    int dcap;
    stage_partition(cnt, bucket, c, f, wv, sIdx, sWt, dcap);
    __syncthreads();

    float dc = dinv[c];
    float acc = bf2f(H[(size_t)c * HID + f]);
    for (int base = 0; base < dcap; base += 16) {
        int idx[16];
        float w[16];
#pragma unroll
        for (int i = 0; i < 16; i++) {
            int l = (base + i < dcap) ? base + i : dcap - 1;
            idx[i] = sIdx[wv][l];
            w[i] = (base + i < dcap) ? sWt[wv][l] : 0.f;
        }
        float v[16];
#pragma unroll
        for (int i = 0; i < 16; i++) v[i] = bf2f(H[(size_t)idx[i] * HID + f]);
#pragma unroll
        for (int i = 0; i < 16; i++) acc = fmaf(v[i], w[i], acc);
    }
    float scale = bng[f] * rsqrtf(1.f + BN_EPS);
    XO[(size_t)c * HID + f] = fmaxf(fmaf(acc * dc + gb[f], scale, bnb[f]), 0.f);
}

// ---------------- x2 [38912][64] -> x2t [64][38912] ----------------
__global__ __launch_bounds__(256) void k_xpose(const float* __restrict__ x2,
                                               float* __restrict__ x2t) {
    __shared__ float tile[64][65];
    int n0 = blockIdx.x * 64;
    for (int i = threadIdx.x; i < 4096; i += 256) {
        int r = i >> 6, h = i & 63;
        tile[r][h] = x2[(size_t)(n0 + r) * 64 + h];
    }
    __syncthreads();
    for (int i = threadIdx.x; i < 4096; i += 256) {
        int h = i >> 6, c = i & 63;
        x2t[(size_t)h * NN + n0 + c] = tile[c][h];
    }
}

// ---------------- fused temporal: packed-fp32, 16 pairs/block, 4 ch/lane ----
__global__ __launch_bounds__(256) void k_temporal2(
    const float* __restrict__ data_x, const float* __restrict__ x2t,
    const float* __restrict__ w1, const float* __restrict__ b1,
    const float* __restrict__ w2, const float* __restrict__ b2,
    const float* __restrict__ w3, const float* __restrict__ b3,
    const float* __restrict__ v1, const float* __restrict__ vb1,
    const float* __restrict__ v2, const float* __restrict__ vb2,
    const float* __restrict__ v3, const float* __restrict__ vb3,
    const float* __restrict__ bn2g, const float* __restrict__ bn2b,
    short* __restrict__ Ab) {
    int bn0 = blockIdx.x * 16;
    int b = bn0 / NODES, node0 = bn0 % NODES;
    int tid = threadIdx.x;
    int p = tid >> 4;
    int c0 = (tid & 15) << 2;
    int node = node0 + p;

    __shared__ float xs[16][22];
    for (int i = tid; i < 320; i += 256) {
        int t = i >> 4, pp = i & 15;
        xs[pp][t + 1] = data_x[b * (TSTEPS * NODES) + t * NODES + node0 + pp];
    }
    if (tid < 16) { xs[tid][0] = 0.f; xs[tid][21] = 0.f; }

    f32x2 A1p[2][3], A2p[2][3], A3p[2][3], B1p[2], B2p[2], B3p[2];
    f32x2 U1p[2][3], U2p[2][3], U3p[2][3];
#pragma unroll
    for (int cp = 0; cp < 2; cp++) {
        int ca = c0 + 2 * cp, cb = ca + 1;
#pragma unroll
        for (int k = 0; k < 3; k++) {
            A1p[cp][k][0] = w1[ca * 3 + k]; A1p[cp][k][1] = w1[cb * 3 + k];
            A2p[cp][k][0] = w2[ca * 3 + k]; A2p[cp][k][1] = w2[cb * 3 + k];
            A3p[cp][k][0] = w3[ca * 3 + k]; A3p[cp][k][1] = w3[cb * 3 + k];
            U1p[cp][k][0] = v1[ca * 3 + k]; U1p[cp][k][1] = v1[cb * 3 + k];
            U2p[cp][k][0] = v2[ca * 3 + k]; U2p[cp][k][1] = v2[cb * 3 + k];
            U3p[cp][k][0] = v3[ca * 3 + k]; U3p[cp][k][1] = v3[cb * 3 + k];
        }
        B1p[cp][0] = b1[ca]; B1p[cp][1] = b1[cb];
        B2p[cp][0] = b2[ca]; B2p[cp][1] = b2[cb];
        B3p[cp][0] = b3[ca]; B3p[cp][1] = b3[cb];
    }
    float cb1 = vb1[0], cb2 = vb2[0], cb3 = vb3[0];
    float s2 = bn2g[node] * rsqrtf(1.f + BN_EPS);
    float bb2 = bn2b[node];
    short* dst = Ab + (size_t)b * KP1;

    __syncthreads();

    f32x2 hA2[2] = {}, hB2[2] = {}, hC2[2];
    float xr0 = xs[p][0], xr1 = xs[p][1];

#pragma unroll
    for (int j = 0; j <= 21; j++) {
        if (j < 20) {
            float xr2 = xs[p][j + 2];
            f32x2 x0d, x1d, x2d;
            x0d[0] = xr0; x0d[1] = xr0;
            x1d[0] = xr1; x1d[1] = xr1;
            x2d[0] = xr2; x2d[1] = xr2;
#pragma unroll
            for (int cp = 0; cp < 2; cp++) {
                f32x2 pv = pk_fma(A1p[cp][2], x2d,
                            pk_fma(A1p[cp][1], x1d, pk_fma(A1p[cp][0], x0d, B1p[cp])));
                f32x2 qv = pk_fma(A2p[cp][2], x2d,
                            pk_fma(A2p[cp][1], x1d, pk_fma(A2p[cp][0], x0d, B2p[cp])));
                f32x2 rv = pk_fma(A3p[cp][2], x2d,
                            pk_fma(A3p[cp][1], x1d, pk_fma(A3p[cp][0], x0d, B3p[cp])));
                hC2[cp][0] = fmaxf(fmaf(pv[0], fast_sigmoid(qv[0]), rv[0]), 0.f);
                hC2[cp][1] = fmaxf(fmaf(pv[1], fast_sigmoid(qv[1]), rv[1]), 0.f);
            }
            xr0 = xr1;
            xr1 = xr2;
        } else if (j == 20) {
            const float4 gv = *(const float4*)(x2t + (size_t)(b >> 1) * NN +
                                               (b & 1) * (NODES * HID) + node * HID + c0);
            hC2[0][0] = fmaxf(gv.x, 0.f);
            hC2[0][1] = fmaxf(gv.y, 0.f);
            hC2[1][0] = fmaxf(gv.z, 0.f);
            hC2[1][1] = fmaxf(gv.w, 0.f);
        } else {
            hC2[0][0] = 0.f; hC2[0][1] = 0.f;
            hC2[1][0] = 0.f; hC2[1][1] = 0.f;
        }
        if (j >= 1) {
            int w = j - 1;
            f32x2 pa, qa, ra;
            pa[0] = 0.f; pa[1] = 0.f;
            qa[0] = 0.f; qa[1] = 0.f;
            ra[0] = 0.f; ra[1] = 0.f;
#pragma unroll
            for (int cp = 0; cp < 2; cp++) {
                pa = pk_fma(U1p[cp][0], hA2[cp], pa);
                pa = pk_fma(U1p[cp][1], hB2[cp], pa);
                pa = pk_fma(U1p[cp][2], hC2[cp], pa);
                qa = pk_fma(U2p[cp][0], hA2[cp], qa);
                qa = pk_fma(U2p[cp][1], hB2[cp], qa);
                qa = pk_fma(U2p[cp][2], hC2[cp], qa);
                ra = pk_fma(U3p[cp][0], hA2[cp], ra);
                ra = pk_fma(U3p[cp][1], hB2[cp], ra);
                ra = pk_fma(U3p[cp][2], hC2[cp], ra);
            }
            float pp_ = rsum16(pa[0] + pa[1]);
            float qq_ = rsum16(qa[0] + qa[1]);
            float rr_ = rsum16(ra[0] + ra[1]);
            float P = pp_ + cb1, Q = qq_ + cb2, R = rr_ + cb3;
            float hv = fmaxf(fmaf(P, fast_sigmoid(Q), R), 0.f);
            if ((tid & 15) == 0) dst[w * NODES + node] = f2bf(fmaf(hv, s2, bb2));
        }
        hA2[0] = hB2[0]; hA2[1] = hB2[1];
        hB2[0] = hC2[0]; hB2[1] = hC2[1];
    }
}

// fc4W [2048][300] f32 -> W4t [304][2048] bf16 (transposed, N-padded)
__global__ __launch_bounds__(256) void k_cvtW4(const float* __restrict__ W,
                                               short* __restrict__ Wt) {
    __shared__ float t[32][33];
    int tx = threadIdx.x & 31, ty = threadIdx.x >> 5;
    int n0 = blockIdx.x * 32, k0 = blockIdx.y * 32;
#pragma unroll
    for (int r = 0; r < 32; r += 8) {
        int k = k0 + r + ty, n = n0 + tx;
        t[r + ty][tx] = (n < FC2_OUT) ? W[(size_t)k * FC2_OUT + n] : 0.f;
    }
    __syncthreads();
#pragma unroll
    for (int r = 0; r < 32; r += 8) {
        int n = n0 + r + ty;
        if (n < NP2) Wt[(size_t)n * FC1_OUT + k0 + tx] = f2bf(t[tx][r + ty]);
    }
}

// ---------------- FC1 MFMA GEMM, B read directly from f32 fcW ----------------
#define KSPL1 8
#define KCH1  (KP1 / KSPL1)  // 800
__global__ __launch_bounds__(256) void k_gemm1f(const short* __restrict__ Ab,
                                                const float* __restrict__ fcW,
                                                float* __restrict__ part) {
    int lane = threadIdx.x & 63, wv = threadIdx.x >> 6;
    int r = lane & 15, kg = lane >> 4;
    int nb = blockIdx.x * 64, sp = blockIdx.y;

    f32x4 acc[2][4] = {};
    const short* a0 = Ab + (size_t)(wv * 32 + r) * KP1;
    const short* a1 = a0 + (size_t)16 * KP1;

    int k0 = sp * KCH1 + kg * 8;
    const float* wp = fcW + (size_t)k0 * FC1_OUT + nb + r;
    bool tailblk = (sp == KSPL1 - 1);

#pragma unroll 1
    for (int s = 0; s < KCH1 / 32; s++, k0 += 32) {
        short8 av0 = *(const short8*)(a0 + k0);
        short8 av1 = *(const short8*)(a1 + k0);
        short8 bv[4];
        if (tailblk && s == KCH1 / 32 - 1) {
#pragma unroll
            for (int f = 0; f < 4; f++)
#pragma unroll
                for (int i = 0; i < 8; i++) {
                    float v = (k0 + i < FC1_IN) ? wp[(size_t)i * FC1_OUT + f * 16] : 0.f;
                    bv[f][i] = f2bf(v);
                }
        } else {
#pragma unroll
            for (int f = 0; f < 4; f++)
#pragma unroll
                for (int i = 0; i < 8; i++)
                    bv[f][i] = f2bf(wp[(size_t)i * FC1_OUT + f * 16]);
        }
        acc[0][0] = __builtin_amdgcn_mfma_f32_16x16x32_bf16(av0, bv[0], acc[0][0], 0, 0, 0);
        acc[1][0] = __builtin_amdgcn_mfma_f32_16x16x32_bf16(av1, bv[0], acc[1][0], 0, 0, 0);
        acc[0][1] = __builtin_amdgcn_mfma_f32_16x16x32_bf16(av0, bv[1], acc[0][1], 0, 0, 0);
        acc[1][1] = __builtin_amdgcn_mfma_f32_16x16x32_bf16(av1, bv[1], acc[1][1], 0, 0, 0);
        acc[0][2] = __builtin_amdgcn_mfma_f32_16x16x32_bf16(av0, bv[2], acc[0][2], 0, 0, 0);
        acc[1][2] = __builtin_amdgcn_mfma_f32_16x16x32_bf16(av1, bv[2], acc[1][2], 0, 0, 0);
        acc[0][3] = __builtin_amdgcn_mfma_f32_16x16x32_bf16(av0, bv[3], acc[0][3], 0, 0, 0);
        acc[1][3] = __builtin_amdgcn_mfma_f32_16x16x32_bf16(av1, bv[3], acc[1][3], 0, 0, 0);
        wp += (size_t)32 * FC1_OUT;
    }

    float* dst = part + (size_t)sp * BATCH * FC1_OUT;
#pragma unroll
    for (int m = 0; m < 2; m++)
#pragma unroll
        for (int f = 0; f < 4; f++)
#pragma unroll
            for (int j = 0; j < 4; j++) {
                int row = wv * 32 + m * 16 + kg * 4 + j;
                int col = nb + f * 16 + r;
                dst[(size_t)row * FC1_OUT + col] = acc[m][f][j];
            }
}

// reduce split-K + bias + ReLU -> bf16 activations for FC2
__global__ __launch_bounds__(256) void k_reduce1(const float* __restrict__ part,
                                                 const float* __restrict__ bias,
                                                 short* __restrict__ Ab2) {
    int idx = blockIdx.x * 256 + threadIdx.x;
    int o = idx & (FC1_OUT - 1);
    float s = bias[o];
#pragma unroll
    for (int sp = 0; sp < KSPL1; sp++) s += part[(size_t)sp * BATCH * FC1_OUT + idx];
    Ab2[idx] = f2bf(fmaxf(s, 0.f));
}

// ---------------- FC2 MFMA GEMM ----------------
#define KSPL2 8
#define KCH2  (FC1_OUT / KSPL2)  // 256
__global__ __launch_bounds__(256) void k_gemm2(const short* __restrict__ Ab,
                                               const short* __restrict__ Wt,
                                               float* __restrict__ part) {
    int lane = threadIdx.x & 63, wv = threadIdx.x >> 6;
    int r = lane & 15, kg = lane >> 4;
    int nb = blockIdx.x * 16, sp = blockIdx.y;

    f32x4 acc[2] = {};
    const short* a0 = Ab + (size_t)(wv * 32 + r) * FC1_OUT;
    const short* a1 = a0 + (size_t)16 * FC1_OUT;
    const short* bp = Wt + (size_t)(nb + r) * FC1_OUT;

    int k0 = sp * KCH2 + kg * 8;
#pragma unroll
    for (int s = 0; s < KCH2 / 32; s++, k0 += 32) {
        short8 av0 = *(const short8*)(a0 + k0);
        short8 av1 = *(const short8*)(a1 + k0);
        short8 bv = *(const short8*)(bp + k0);
        acc[0] = __builtin_amdgcn_mfma_f32_16x16x32_bf16(av0, bv, acc[0], 0, 0, 0);
        acc[1] = __builtin_amdgcn_mfma_f32_16x16x32_bf16(av1, bv, acc[1], 0, 0, 0);
    }

    float* dst = part + (size_t)sp * BATCH * NP2;
#pragma unroll
    for (int m = 0; m < 2; m++)
#pragma unroll
        for (int j = 0; j < 4; j++) {
            int row = wv * 32 + m * 16 + kg * 4 + j;
            int col = nb + r;
            dst[(size_t)row * NP2 + col] = acc[m][j];
        }
}

__global__ __launch_bounds__(256) void k_reduce2(const float* __restrict__ part,
                                                 const float* __restrict__ bias,
                                                 float* __restrict__ out) {
    int idx = blockIdx.x * 256 + threadIdx.x;
    if (idx >= BATCH * NP2) return;
    int b = idx / NP2, o = idx % NP2;
    float s = 0.f;
#pragma unroll
    for (int sp = 0; sp < KSPL2; sp++) s += part[(size_t)sp * BATCH * NP2 + idx];
    if (o < FC2_OUT) out[(size_t)b * FC2_OUT + o] = s + bias[o];
}

extern "C" void kernel_launch(void* const* d_in, const int* in_sizes, int n_in,
                              void* d_out, int out_size, void* d_ws, size_t ws_size,
                              hipStream_t stream) {
    const float* data_x = (const float*)d_in[0];
    const int* ei = (const int*)d_in[1];
    const float* ew = (const float*)d_in[2];
    const float* tc1w1 = (const float*)d_in[3];
    const float* tc1b1 = (const float*)d_in[4];
    const float* tc1w2 = (const float*)d_in[5];
    const float* tc1b2 = (const float*)d_in[6];
    const float* tc1w3 = (const float*)d_in[7];
    const float* tc1b3 = (const float*)d_in[8];
    const float* W0 = (const float*)d_in[9];
    const float* gb0 = (const float*)d_in[10];
    const float* bn0g = (const float*)d_in[11];
    const float* bn0b = (const float*)d_in[12];
    const float* W1 = (const float*)d_in[13];
    const float* gb1 = (const float*)d_in[14];
    const float* bn1g = (const float*)d_in[15];
    const float* bn1b = (const float*)d_in[16];
    const float* tc2w1 = (const float*)d_in[17];
    const float* tc2b1 = (const float*)d_in[18];
    const float* tc2w2 = (const float*)d_in[19];
    const float* tc2b2 = (const float*)d_in[20];
    const float* tc2w3 = (const float*)d_in[21];
    const float* tc2b3 = (const float*)d_in[22];
    const float* bn2g = (const float*)d_in[23];
    const float* bn2b = (const float*)d_in[24];
    const float* fcW = (const float*)d_in[25];
    const float* fcb = (const float*)d_in[26];
    const float* fc4W = (const float*)d_in[27];
    const float* fc4b = (const float*)d_in[28];
    float* out = (float*)d_out;

    char* ws = (char*)d_ws;
    // persistent: x2 (gfeat source) + Ab (FC1 bf16 activations)
    float* x2 = (float*)(ws + 0);                  // 9,961,472 B
    short* Ab = (short*)(ws + 9961472);            // 1,638,400 B
    const size_t ARENA = 9961472 + 1638400;        // 11,599,872

    // arena A (graph phase): bucket + cnt + dinv + h0 + h1
    size_t off = ARENA;
    auto alloc = [&](size_t bytes) -> void* {
        void* p = ws + off;
        off = (off + bytes + 255) & ~(size_t)255;
        return p;
    };
    int2* bucket = (int2*)alloc((size_t)NN * BCAP * 8);  // 19.9 MB
    int* cnt = (int*)alloc((size_t)NN * 4);
    float* dinv = (float*)alloc((size_t)NN * 4);
    unsigned short* h0 = (unsigned short*)alloc((size_t)NN * HID * 2);
    unsigned short* h1 = (unsigned short*)alloc((size_t)NN * HID * 2);

    // x2t overlaps arena A (bucket region dead after gatherB)
    float* x2t = (float*)(ws + ARENA);             // 9,961,472 B

    // arena C (FC phase) — overlaps arena A and x2t, used only after temporal
    off = ARENA;
    float* part1 = (float*)alloc((size_t)KSPL1 * BATCH * FC1_OUT * 4);
    short* Ab2 = (short*)alloc((size_t)BATCH * FC1_OUT * 2);
    short* W4t = (short*)alloc((size_t)NP2 * FC1_OUT * 2);
    float* part2 = (float*)alloc((size_t)KSPL2 * BATCH * NP2 * 4);
    (void)ws_size; (void)in_sizes; (void)n_in; (void)out_size;

    // ---- bucketed edge build (1 global atomic/edge; no scan, no fill) ----
    hipMemsetAsync(cnt, 0, (size_t)NN * 4, stream);
    k_bucket<<<(NE + 255) / 256, 256, 0, stream>>>(ei, ew, cnt, bucket);
    k_dinv2<<<(NN + 255) / 256, 256, 0, stream>>>(cnt, bucket, dinv);

    // ---- GCN (pre-scaled bf16 features; ballot-partitioned gathers) ----
    k_mm20<<<NN / 4, 256, 0, stream>>>(data_x, W0, dinv, h0);
    k_gatherA<<<NN / 4, 256, 0, stream>>>(cnt, bucket, dinv, h0, gb0, bn0g, bn0b,
                                          W1, h1);
    k_gatherB<<<NN / 4, 256, 0, stream>>>(cnt, bucket, dinv, h1, gb1, bn1g, bn1b, x2);

    // ---- transpose x2 for coalesced gfeat ----
    k_xpose<<<NN / 64, 256, 0, stream>>>(x2, x2t);

    // ---- temporal (fused conv1 + concat + conv2 + BN2d, packed fp32) -> bf16 Ab ----
    hipMemsetAsync(Ab, 0, (size_t)BATCH * KP1 * 2, stream);  // zero K-padding
    k_temporal2<<<NN / 16, 256, 0, stream>>>(data_x, x2t, tc1w1, tc1b1, tc1w2, tc1b2,
                                             tc1w3, tc1b3, tc2w1, tc2b1, tc2w2, tc2b2,
                                             tc2w3, tc2b3, bn2g, bn2b, Ab);

    // ---- FC (bf16 MFMA) ----
    {
        dim3 g(FC1_OUT / 64, KSPL1);
        k_gemm1f<<<g, 256, 0, stream>>>(Ab, fcW, part1);
    }
    k_reduce1<<<BATCH * FC1_OUT / 256, 256, 0, stream>>>(part1, fcb, Ab2);
    {
        dim3 g((NP2 + 31) / 32, FC1_OUT / 32);
        k_cvtW4<<<g, 256, 0, stream>>>(fc4W, W4t);
    }
    {
        dim3 g(NP2 / 16, KSPL2);
        k_gemm2<<<g, 256, 0, stream>>>(Ab2, W4t, part2);
    }
    k_reduce2<<<(BATCH * NP2 + 255) / 256, 256, 0, stream>>>(part2, fc4b, out);
}

// Round 9
// 205.723 us; speedup vs baseline: 2.0306x; 1.0435x over previous
//
#include <hip/hip_runtime.h>

#define NODES   304
#define BATCH   128
#define TSTEPS  20
#define HID     64
#define GCNIN   20
#define NN      (BATCH*NODES)      // 38912
#define NE      (NN*16)            // 622592
#define SEGSZ   (NN/4)             // 9728 (row-quarter for L2 phasing)
#define BCAP    64                 // bucket capacity per col
#define FC1_IN  (21*NODES)         // 6384
#define KP1     6400               // FC1_IN padded to /32
#define FC1_OUT 2048
#define FC2_OUT 300
#define NP2     304                // FC2_OUT padded to /16
#define BN_EPS  1e-5f

typedef __attribute__((ext_vector_type(8))) short short8;
typedef __attribute__((ext_vector_type(4))) float f32x4;
typedef __attribute__((ext_vector_type(2))) float f32x2;

static __device__ __forceinline__ short f2bf(float x) {
    unsigned u = __float_as_uint(x);
    unsigned r = (u + 0x7FFF + ((u >> 16) & 1)) >> 16;  // RNE
    return (short)r;
}
static __device__ __forceinline__ float bf2f(unsigned short v) {
    return __uint_as_float((unsigned)v << 16);
}

static __device__ __forceinline__ float fast_sigmoid(float q) {
    return __builtin_amdgcn_rcpf(1.f + __expf(-q));
}

// packed fp32 FMA (VOP3P) — 2x fp32 rate on CDNA4
static __device__ __forceinline__ f32x2 pk_fma(f32x2 a, f32x2 b, f32x2 c) {
    f32x2 d;
    asm("v_pk_fma_f32 %0, %1, %2, %3" : "=v"(d) : "v"(a), "v"(b), "v"(c));
    return d;
}

// DPP row_ror add (VALU pipe, no DS ops)
template <int C>
static __device__ __forceinline__ float dppadd(float v) {
    return v + __int_as_float(
        __builtin_amdgcn_update_dpp(0, __float_as_int(v), C, 0xF, 0xF, false));
}
static __device__ __forceinline__ float rsum16(float v) {
    v = dppadd<0x128>(v);
    v = dppadd<0x124>(v);
    v = dppadd<0x122>(v);
    v = dppadd<0x121>(v);
    return v;
}

// ---------------- bucketed edge build: ONE global atomic per edge ----------------
__global__ void k_bucket(const int* __restrict__ ei, const float* __restrict__ ew,
                         int* __restrict__ cnt, int2* __restrict__ bucket) {
    int e = blockIdx.x * blockDim.x + threadIdx.x;
    if (e < NE) {
        int c = ei[NE + e];
        int slot = atomicAdd(&cnt[c], 1);
        if (slot < BCAP) {
            int2 v;
            v.x = ei[e];
            v.y = __float_as_int(ew[e]);
            bucket[((size_t)c << 6) + slot] = v;
        }
    }
}

// ---------------- h0' = dinv * (data_x @ W0) -> bf16 ; also computes dinv ----------
__global__ __launch_bounds__(256) void k_mm20(const float* __restrict__ X,
                                              const float* __restrict__ W,
                                              const int* __restrict__ cnt,
                                              const int2* __restrict__ bucket,
                                              unsigned short* __restrict__ H,
                                              float* __restrict__ dinv) {
    int wv = threadIdx.x >> 6, f = threadIdx.x & 63;
    int n = blockIdx.x * 4 + wv;
    __shared__ float xs[4][GCNIN];
    __shared__ float rs[4][4];

    // issue independent loads up front
    int2 be = bucket[((size_t)n << 6) + f];   // unconditional (always in-bounds)
    int deg = cnt[n];
    if (f < GCNIN) xs[wv][f] = X[(size_t)n * GCNIN + f];

    int dcap = deg < BCAP ? deg : BCAP;
    float wsum = (f < dcap) ? __int_as_float(be.y) : 0.f;
    wsum = rsum16(wsum);
    if ((f & 15) == 0) rs[wv][f >> 4] = wsum;
    __syncthreads();

    float dv = rsqrtf(fmaxf(1.f + rs[wv][0] + rs[wv][1] + rs[wv][2] + rs[wv][3],
                            1e-12f));
    if (f == 0) dinv[n] = dv;

    float acc = 0.f;
#pragma unroll
    for (int k = 0; k < GCNIN; k++) acc = fmaf(xs[wv][k], W[k * HID + f], acc);
    H[(size_t)n * HID + f] = (unsigned short)f2bf(acc * dv);
}

// ballot-partition the wave's staged edges by row-quarter (L2 phasing);
// bucket entry is passed in pre-loaded (no cnt->bucket serial dependency)
static __device__ __forceinline__ void stage_partition(
    int deg, int2 e, int f, int wv, int (*sIdx)[BCAP], float (*sWt)[BCAP],
    int& dcap) {
    dcap = deg < BCAP ? deg : BCAP;
    bool valid = f < dcap;
    int row = e.x;
    float w = __int_as_float(e.y);
    int q = (row >= SEGSZ) + (row >= 2 * SEGSZ) + (row >= 3 * SEGSZ);
    unsigned long long b0 = __ballot(valid && q == 0);
    unsigned long long b1 = __ballot(valid && q == 1);
    unsigned long long b2 = __ballot(valid && q == 2);
    unsigned long long b3 = __ballot(valid && q == 3);
    unsigned long long lmask = (1ULL << f) - 1;
    int pos = 0;
    if (q > 0) pos += __popcll(b0);
    if (q > 1) pos += __popcll(b1);
    if (q > 2) pos += __popcll(b2);
    unsigned long long mybal = (q == 0) ? b0 : (q == 1) ? b1 : (q == 2) ? b2 : b3;
    pos += __popcll(mybal & lmask);
    if (valid) {
        sIdx[wv][pos] = row;
        sWt[wv][pos] = w;
    }
}

// ------- layer0 gather (pre-scaled bf16 feats) + BN + ReLU + matvec @W1 -------
__global__ __launch_bounds__(256) void k_gatherA(const int* __restrict__ cnt,
                                                 const int2* __restrict__ bucket,
                                                 const float* __restrict__ dinv,
                                                 const unsigned short* __restrict__ H0,
                                                 const float* __restrict__ gb,
                                                 const float* __restrict__ bng,
                                                 const float* __restrict__ bnb,
                                                 const float* __restrict__ W1,
                                                 unsigned short* __restrict__ H1) {
    int wv = threadIdx.x >> 6, f = threadIdx.x & 63;
    int c = blockIdx.x * 4 + wv;
    __shared__ int sIdx[4][BCAP];
    __shared__ float sWt[4][BCAP];
    __shared__ float xs[4][HID];

    // issue all block-start loads in parallel
    int2 be = bucket[((size_t)c << 6) + f];
    int deg = cnt[c];
    float dc = dinv[c];
    float self = bf2f(H0[(size_t)c * HID + f]);

    int dcap;
    stage_partition(deg, be, f, wv, sIdx, sWt, dcap);
    __syncthreads();

    float acc = self;  // self loop (pre-scaled)
    for (int base = 0; base < dcap; base += 16) {
        int idx[16];
        float w[16];
#pragma unroll
        for (int i = 0; i < 16; i++) {
            int l = (base + i < dcap) ? base + i : dcap - 1;
            idx[i] = sIdx[wv][l];
            w[i] = (base + i < dcap) ? sWt[wv][l] : 0.f;
        }
        float v[16];
#pragma unroll
        for (int i = 0; i < 16; i++) v[i] = bf2f(H0[(size_t)idx[i] * HID + f]);
#pragma unroll
        for (int i = 0; i < 16; i++) acc = fmaf(v[i], w[i], acc);
    }
    float scale = bng[f] * rsqrtf(1.f + BN_EPS);
    float y = fmaxf(fmaf(acc * dc + gb[f], scale, bnb[f]), 0.f);  // x1[c][f]

    xs[wv][f] = y;
    __syncthreads();
    float h = 0.f;
#pragma unroll
    for (int k4 = 0; k4 < HID / 4; k4++) {
        float4 xv = *(const float4*)&xs[wv][k4 * 4];
        h = fmaf(xv.x, W1[(k4 * 4 + 0) * HID + f], h);
        h = fmaf(xv.y, W1[(k4 * 4 + 1) * HID + f], h);
        h = fmaf(xv.z, W1[(k4 * 4 + 2) * HID + f], h);
        h = fmaf(xv.w, W1[(k4 * 4 + 3) * HID + f], h);
    }
    H1[(size_t)c * HID + f] = (unsigned short)f2bf(h * dc);  // pre-scaled
}

// -------- layer1 gather (pre-scaled bf16 feats) + BN + ReLU -> x2 f32 --------
__global__ __launch_bounds__(256) void k_gatherB(const int* __restrict__ cnt,
                                                 const int2* __restrict__ bucket,
                                                 const float* __restrict__ dinv,
                                                 const unsigned short* __restrict__ H,
                                                 const float* __restrict__ gb,
                                                 const float* __restrict__ bng,
                                                 const float* __restrict__ bnb,
                                                 float* __restrict__ XO) {
    int wv = threadIdx.x >> 6, f = threadIdx.x & 63;
    int c = blockIdx.x * 4 + wv;
    __shared__ int sIdx[4][BCAP];
    __shared__ float sWt[4][BCAP];

    int2 be = bucket[((size_t)c << 6) + f];
    int deg = cnt[c];
    float dc = dinv[c];
    float self = bf2f(H[(size_t)c * HID + f]);

    int dcap;
    stage_partition(deg, be, f, wv, sIdx, sWt, dcap);
    __syncthreads();

    float acc = self;
    for (int base = 0; base < dcap; base += 16) {
        int idx[16];
        float w[16];
#pragma unroll
        for (int i = 0; i < 16; i++) {
            int l = (base + i < dcap) ? base + i : dcap - 1;
            idx[i] = sIdx[wv][l];
            w[i] = (base + i < dcap) ? sWt[wv][l] : 0.f;
        }
        float v[16];
#pragma unroll
        for (int i = 0; i < 16; i++) v[i] = bf2f(H[(size_t)idx[i] * HID + f]);
#pragma unroll
        for (int i = 0; i < 16; i++) acc = fmaf(v[i], w[i], acc);
    }
    float scale = bng[f] * rsqrtf(1.f + BN_EPS);
    XO[(size_t)c * HID + f] = fmaxf(fmaf(acc * dc + gb[f], scale, bnb[f]), 0.f);
}

// ---------------- x2 [38912][64] -> x2t [64][38912] ----------------
__global__ __launch_bounds__(256) void k_xpose(const float* __restrict__ x2,
                                               float* __restrict__ x2t) {
    __shared__ float tile[64][65];
    int n0 = blockIdx.x * 64;
    for (int i = threadIdx.x; i < 4096; i += 256) {
        int r = i >> 6, h = i & 63;
        tile[r][h] = x2[(size_t)(n0 + r) * 64 + h];
    }
    __syncthreads();
    for (int i = threadIdx.x; i < 4096; i += 256) {
        int h = i >> 6, c = i & 63;
        x2t[(size_t)h * NN + n0 + c] = tile[c][h];
    }
}

// unpack 12 contiguous LDS floats (ch c0..c0+3 × 3 taps) into packed pairs
static __device__ __forceinline__ void load12(const float* base, f32x2 P[2][3]) {
    float4 f0 = *(const float4*)(base);
    float4 f1 = *(const float4*)(base + 4);
    float4 f2 = *(const float4*)(base + 8);
    P[0][0][0] = f0.x; P[0][0][1] = f0.w;
    P[0][1][0] = f0.y; P[0][1][1] = f1.x;
    P[0][2][0] = f0.z; P[0][2][1] = f1.y;
    P[1][0][0] = f1.z; P[1][0][1] = f2.y;
    P[1][1][0] = f1.w; P[1][1][1] = f2.z;
    P[1][2][0] = f2.x; P[1][2][1] = f2.w;
}

// ---------------- fused temporal: packed-fp32, LDS weights, 16 pairs/block ----
__global__ __launch_bounds__(256) void k_temporal2(
    const float* __restrict__ data_x, const float* __restrict__ x2t,
    const float* __restrict__ w1, const float* __restrict__ b1,
    const float* __restrict__ w2, const float* __restrict__ b2,
    const float* __restrict__ w3, const float* __restrict__ b3,
    const float* __restrict__ v1, const float* __restrict__ vb1,
    const float* __restrict__ v2, const float* __restrict__ vb2,
    const float* __restrict__ v3, const float* __restrict__ vb3,
    const float* __restrict__ bn2g, const float* __restrict__ bn2b,
    short* __restrict__ Ab) {
    int bn0 = blockIdx.x * 16;
    int b = bn0 / NODES, node0 = bn0 % NODES;
    int tid = threadIdx.x;
    int p = tid >> 4;
    int c0 = (tid & 15) << 2;
    int node = node0 + p;

    __shared__ float xs[16][22];
    __shared__ float wlds[1344];  // 6 arrays x 192 + 3 biases x 64

    // cooperative weight staging (coalesced, once per block)
    if (tid < 192) {
        wlds[tid] = w1[tid];
        wlds[192 + tid] = w2[tid];
        wlds[384 + tid] = w3[tid];
        wlds[576 + tid] = v1[tid];
        wlds[768 + tid] = v2[tid];
        wlds[960 + tid] = v3[tid];
    }
    if (tid < 64) {
        wlds[1152 + tid] = b1[tid];
        wlds[1216 + tid] = b2[tid];
        wlds[1280 + tid] = b3[tid];
    }
    for (int i = tid; i < 320; i += 256) {
        int t = i >> 4, pp = i & 15;
        xs[pp][t + 1] = data_x[b * (TSTEPS * NODES) + t * NODES + node0 + pp];
    }
    if (tid < 16) { xs[tid][0] = 0.f; xs[tid][21] = 0.f; }

    float cb1 = vb1[0], cb2 = vb2[0], cb3 = vb3[0];
    float s2 = bn2g[node] * rsqrtf(1.f + BN_EPS);
    float bb2 = bn2b[node];
    short* dst = Ab + (size_t)b * KP1;

    __syncthreads();

    // per-lane packed weights from LDS (3x ds_read_b128 each)
    f32x2 A1p[2][3], A2p[2][3], A3p[2][3], B1p[2], B2p[2], B3p[2];
    f32x2 U1p[2][3], U2p[2][3], U3p[2][3];
    load12(&wlds[0 + c0 * 3], A1p);
    load12(&wlds[192 + c0 * 3], A2p);
    load12(&wlds[384 + c0 * 3], A3p);
    load12(&wlds[576 + c0 * 3], U1p);
    load12(&wlds[768 + c0 * 3], U2p);
    load12(&wlds[960 + c0 * 3], U3p);
    {
        float4 t1 = *(const float4*)&wlds[1152 + c0];
        float4 t2 = *(const float4*)&wlds[1216 + c0];
        float4 t3 = *(const float4*)&wlds[1280 + c0];
        B1p[0][0] = t1.x; B1p[0][1] = t1.y; B1p[1][0] = t1.z; B1p[1][1] = t1.w;
        B2p[0][0] = t2.x; B2p[0][1] = t2.y; B2p[1][0] = t2.z; B2p[1][1] = t2.w;
        B3p[0][0] = t3.x; B3p[0][1] = t3.y; B3p[1][0] = t3.z; B3p[1][1] = t3.w;
    }

    f32x2 hA2[2] = {}, hB2[2] = {}, hC2[2];
    float xr0 = xs[p][0], xr1 = xs[p][1];

#pragma unroll
    for (int j = 0; j <= 21; j++) {
        if (j < 20) {
            float xr2 = xs[p][j + 2];
            f32x2 x0d, x1d, x2d;
            x0d[0] = xr0; x0d[1] = xr0;
            x1d[0] = xr1; x1d[1] = xr1;
            x2d[0] = xr2; x2d[1] = xr2;
#pragma unroll
            for (int cp = 0; cp < 2; cp++) {
                f32x2 pv = pk_fma(A1p[cp][2], x2d,
                            pk_fma(A1p[cp][1], x1d, pk_fma(A1p[cp][0], x0d, B1p[cp])));
                f32x2 qv = pk_fma(A2p[cp][2], x2d,
                            pk_fma(A2p[cp][1], x1d, pk_fma(A2p[cp][0], x0d, B2p[cp])));
                f32x2 rv = pk_fma(A3p[cp][2], x2d,
                            pk_fma(A3p[cp][1], x1d, pk_fma(A3p[cp][0], x0d, B3p[cp])));
                hC2[cp][0] = fmaxf(fmaf(pv[0], fast_sigmoid(qv[0]), rv[0]), 0.f);
                hC2[cp][1] = fmaxf(fmaf(pv[1], fast_sigmoid(qv[1]), rv[1]), 0.f);
            }
            xr0 = xr1;
            xr1 = xr2;
        } else if (j == 20) {
            const float4 gv = *(const float4*)(x2t + (size_t)(b >> 1) * NN +
                                               (b & 1) * (NODES * HID) + node * HID + c0);
            hC2[0][0] = fmaxf(gv.x, 0.f);
            hC2[0][1] = fmaxf(gv.y, 0.f);
            hC2[1][0] = fmaxf(gv.z, 0.f);
            hC2[1][1] = fmaxf(gv.w, 0.f);
        } else {
            hC2[0][0] = 0.f; hC2[0][1] = 0.f;
            hC2[1][0] = 0.f; hC2[1][1] = 0.f;
        }
        if (j >= 1) {
            int w = j - 1;
            f32x2 pa, qa, ra;
            pa[0] = 0.f; pa[1] = 0.f;
            qa[0] = 0.f; qa[1] = 0.f;
            ra[0] = 0.f; ra[1] = 0.f;
#pragma unroll
            for (int cp = 0; cp < 2; cp++) {
                pa = pk_fma(U1p[cp][0], hA2[cp], pa);
                pa = pk_fma(U1p[cp][1], hB2[cp], pa);
                pa = pk_fma(U1p[cp][2], hC2[cp], pa);
                qa = pk_fma(U2p[cp][0], hA2[cp], qa);
                qa = pk_fma(U2p[cp][1], hB2[cp], qa);
                qa = pk_fma(U2p[cp][2], hC2[cp], qa);
                ra = pk_fma(U3p[cp][0], hA2[cp], ra);
                ra = pk_fma(U3p[cp][1], hB2[cp], ra);
                ra = pk_fma(U3p[cp][2], hC2[cp], ra);
            }
            float pp_ = rsum16(pa[0] + pa[1]);
            float qq_ = rsum16(qa[0] + qa[1]);
            float rr_ = rsum16(ra[0] + ra[1]);
            float P = pp_ + cb1, Q = qq_ + cb2, R = rr_ + cb3;
            float hv = fmaxf(fmaf(P, fast_sigmoid(Q), R), 0.f);
            if ((tid & 15) == 0) dst[w * NODES + node] = f2bf(fmaf(hv, s2, bb2));
        }
        hA2[0] = hB2[0]; hA2[1] = hB2[1];
        hB2[0] = hC2[0]; hB2[1] = hC2[1];
    }
}

// fc4W [2048][300] f32 -> W4t [304][2048] bf16 (transposed, N-padded)
__global__ __launch_bounds__(256) void k_cvtW4(const float* __restrict__ W,
                                               short* __restrict__ Wt) {
    __shared__ float t[32][33];
    int tx = threadIdx.x & 31, ty = threadIdx.x >> 5;
    int n0 = blockIdx.x * 32, k0 = blockIdx.y * 32;
#pragma unroll
    for (int r = 0; r < 32; r += 8) {
        int k = k0 + r + ty, n = n0 + tx;
        t[r + ty][tx] = (n < FC2_OUT) ? W[(size_t)k * FC2_OUT + n] : 0.f;
    }
    __syncthreads();
#pragma unroll
    for (int r = 0; r < 32; r += 8) {
        int n = n0 + r + ty;
        if (n < NP2) Wt[(size_t)n * FC1_OUT + k0 + tx] = f2bf(t[tx][r + ty]);
    }
}

// ---------------- FC1 MFMA GEMM, B read directly from f32 fcW ----------------
#define KSPL1 8
#define KCH1  (KP1 / KSPL1)  // 800
__global__ __launch_bounds__(256) void k_gemm1f(const short* __restrict__ Ab,
                                                const float* __restrict__ fcW,
                                                float* __restrict__ part) {
    int lane = threadIdx.x & 63, wv = threadIdx.x >> 6;
    int r = lane & 15, kg = lane >> 4;
    int nb = blockIdx.x * 64, sp = blockIdx.y;

    f32x4 acc[2][4] = {};
    const short* a0 = Ab + (size_t)(wv * 32 + r) * KP1;
    const short* a1 = a0 + (size_t)16 * KP1;

    int k0 = sp * KCH1 + kg * 8;
    const float* wp = fcW + (size_t)k0 * FC1_OUT + nb + r;
    bool tailblk = (sp == KSPL1 - 1);

#pragma unroll 1
    for (int s = 0; s < KCH1 / 32; s++, k0 += 32) {
        short8 av0 = *(const short8*)(a0 + k0);
        short8 av1 = *(const short8*)(a1 + k0);
        short8 bv[4];
        if (tailblk && s == KCH1 / 32 - 1) {
#pragma unroll
            for (int f = 0; f < 4; f++)
#pragma unroll
                for (int i = 0; i < 8; i++) {
                    float v = (k0 + i < FC1_IN) ? wp[(size_t)i * FC1_OUT + f * 16] : 0.f;
                    bv[f][i] = f2bf(v);
                }
        } else {
#pragma unroll
            for (int f = 0; f < 4; f++)
#pragma unroll
                for (int i = 0; i < 8; i++)
                    bv[f][i] = f2bf(wp[(size_t)i * FC1_OUT + f * 16]);
        }
        acc[0][0] = __builtin_amdgcn_mfma_f32_16x16x32_bf16(av0, bv[0], acc[0][0], 0, 0, 0);
        acc[1][0] = __builtin_amdgcn_mfma_f32_16x16x32_bf16(av1, bv[0], acc[1][0], 0, 0, 0);
        acc[0][1] = __builtin_amdgcn_mfma_f32_16x16x32_bf16(av0, bv[1], acc[0][1], 0, 0, 0);
        acc[1][1] = __builtin_amdgcn_mfma_f32_16x16x32_bf16(av1, bv[1], acc[1][1], 0, 0, 0);
        acc[0][2] = __builtin_amdgcn_mfma_f32_16x16x32_bf16(av0, bv[2], acc[0][2], 0, 0, 0);
        acc[1][2] = __builtin_amdgcn_mfma_f32_16x16x32_bf16(av1, bv[2], acc[1][2], 0, 0, 0);
        acc[0][3] = __builtin_amdgcn_mfma_f32_16x16x32_bf16(av0, bv[3], acc[0][3], 0, 0, 0);
        acc[1][3] = __builtin_amdgcn_mfma_f32_16x16x32_bf16(av1, bv[3], acc[1][3], 0, 0, 0);
        wp += (size_t)32 * FC1_OUT;
    }

    float* dst = part + (size_t)sp * BATCH * FC1_OUT;
#pragma unroll
    for (int m = 0; m < 2; m++)
#pragma unroll
        for (int f = 0; f < 4; f++)
#pragma unroll
            for (int j = 0; j < 4; j++) {
                int row = wv * 32 + m * 16 + kg * 4 + j;
                int col = nb + f * 16 + r;
                dst[(size_t)row * FC1_OUT + col] = acc[m][f][j];
            }
}

// reduce split-K + bias + ReLU -> bf16 activations for FC2
__global__ __launch_bounds__(256) void k_reduce1(const float* __restrict__ part,
                                                 const float* __restrict__ bias,
                                                 short* __restrict__ Ab2) {
    int idx = blockIdx.x * 256 + threadIdx.x;
    int o = idx & (FC1_OUT - 1);
    float s = bias[o];
#pragma unroll
    for (int sp = 0; sp < KSPL1; sp++) s += part[(size_t)sp * BATCH * FC1_OUT + idx];
    Ab2[idx] = f2bf(fmaxf(s, 0.f));
}

// ---------------- FC2 MFMA GEMM ----------------
#define KSPL2 8
#define KCH2  (FC1_OUT / KSPL2)  // 256
__global__ __launch_bounds__(256) void k_gemm2(const short* __restrict__ Ab,
                                               const short* __restrict__ Wt,
                                               float* __restrict__ part) {
    int lane = threadIdx.x & 63, wv = threadIdx.x >> 6;
    int r = lane & 15, kg = lane >> 4;
    int nb = blockIdx.x * 16, sp = blockIdx.y;

    f32x4 acc[2] = {};
    const short* a0 = Ab + (size_t)(wv * 32 + r) * FC1_OUT;
    const short* a1 = a0 + (size_t)16 * FC1_OUT;
    const short* bp = Wt + (size_t)(nb + r) * FC1_OUT;

    int k0 = sp * KCH2 + kg * 8;
#pragma unroll
    for (int s = 0; s < KCH2 / 32; s++, k0 += 32) {
        short8 av0 = *(const short8*)(a0 + k0);
        short8 av1 = *(const short8*)(a1 + k0);
        short8 bv = *(const short8*)(bp + k0);
        acc[0] = __builtin_amdgcn_mfma_f32_16x16x32_bf16(av0, bv, acc[0], 0, 0, 0);
        acc[1] = __builtin_amdgcn_mfma_f32_16x16x32_bf16(av1, bv, acc[1], 0, 0, 0);
    }

    float* dst = part + (size_t)sp * BATCH * NP2;
#pragma unroll
    for (int m = 0; m < 2; m++)
#pragma unroll
        for (int j = 0; j < 4; j++) {
            int row = wv * 32 + m * 16 + kg * 4 + j;
            int col = nb + r;
            dst[(size_t)row * NP2 + col] = acc[m][j];
        }
}

__global__ __launch_bounds__(256) void k_reduce2(const float* __restrict__ part,
                                                 const float* __restrict__ bias,
                                                 float* __restrict__ out) {
    int idx = blockIdx.x * 256 + threadIdx.x;
    if (idx >= BATCH * NP2) return;
    int b = idx / NP2, o = idx % NP2;
    float s = 0.f;
#pragma unroll
    for (int sp = 0; sp < KSPL2; sp++) s += part[(size_t)sp * BATCH * NP2 + idx];
    if (o < FC2_OUT) out[(size_t)b * FC2_OUT + o] = s + bias[o];
}

extern "C" void kernel_launch(void* const* d_in, const int* in_sizes, int n_in,
                              void* d_out, int out_size, void* d_ws, size_t ws_size,
                              hipStream_t stream) {
    const float* data_x = (const float*)d_in[0];
    const int* ei = (const int*)d_in[1];
    const float* ew = (const float*)d_in[2];
    const float* tc1w1 = (const float*)d_in[3];
    const float* tc1b1 = (const float*)d_in[4];
    const float* tc1w2 = (const float*)d_in[5];
    const float* tc1b2 = (const float*)d_in[6];
    const float* tc1w3 = (const float*)d_in[7];
    const float* tc1b3 = (const float*)d_in[8];
    const float* W0 = (const float*)d_in[9];
    const float* gb0 = (const float*)d_in[10];
    const float* bn0g = (const float*)d_in[11];
    const float* bn0b = (const float*)d_in[12];
    const float* W1 = (const float*)d_in[13];
    const float* gb1 = (const float*)d_in[14];
    const float* bn1g = (const float*)d_in[15];
    const float* bn1b = (const float*)d_in[16];
    const float* tc2w1 = (const float*)d_in[17];
    const float* tc2b1 = (const float*)d_in[18];
    const float* tc2w2 = (const float*)d_in[19];
    const float* tc2b2 = (const float*)d_in[20];
    const float* tc2w3 = (const float*)d_in[21];
    const float* tc2b3 = (const float*)d_in[22];
    const float* bn2g = (const float*)d_in[23];
    const float* bn2b = (const float*)d_in[24];
    const float* fcW = (const float*)d_in[25];
    const float* fcb = (const float*)d_in[26];
    const float* fc4W = (const float*)d_in[27];
    const float* fc4b = (const float*)d_in[28];
    float* out = (float*)d_out;

    char* ws = (char*)d_ws;
    // persistent: x2 (gfeat source) + Ab (FC1 bf16 activations)
    float* x2 = (float*)(ws + 0);                  // 9,961,472 B
    short* Ab = (short*)(ws + 9961472);            // 1,638,400 B
    const size_t ARENA = 9961472 + 1638400;        // 11,599,872

    // arena A (graph phase): bucket + cnt + dinv + h0 + h1
    size_t off = ARENA;
    auto alloc = [&](size_t bytes) -> void* {
        void* p = ws + off;
        off = (off + bytes + 255) & ~(size_t)255;
        return p;
    };
    int2* bucket = (int2*)alloc((size_t)NN * BCAP * 8);  // 19.9 MB
    int* cnt = (int*)alloc((size_t)NN * 4);
    float* dinv = (float*)alloc((size_t)NN * 4);
    unsigned short* h0 = (unsigned short*)alloc((size_t)NN * HID * 2);
    unsigned short* h1 = (unsigned short*)alloc((size_t)NN * HID * 2);

    // x2t overlaps arena A (bucket region dead after gatherB)
    float* x2t = (float*)(ws + ARENA);             // 9,961,472 B

    // arena C (FC phase) — overlaps arena A and x2t, used only after temporal
    off = ARENA;
    float* part1 = (float*)alloc((size_t)KSPL1 * BATCH * FC1_OUT * 4);
    short* Ab2 = (short*)alloc((size_t)BATCH * FC1_OUT * 2);
    short* W4t = (short*)alloc((size_t)NP2 * FC1_OUT * 2);
    float* part2 = (float*)alloc((size_t)KSPL2 * BATCH * NP2 * 4);
    (void)ws_size; (void)in_sizes; (void)n_in; (void)out_size;

    // ---- bucketed edge build ----
    hipMemsetAsync(cnt, 0, (size_t)NN * 4, stream);
    k_bucket<<<(NE + 255) / 256, 256, 0, stream>>>(ei, ew, cnt, bucket);

    // ---- GCN (dinv fused into mm20; ballot-partitioned gathers) ----
    k_mm20<<<NN / 4, 256, 0, stream>>>(data_x, W0, cnt, bucket, h0, dinv);
    k_gatherA<<<NN / 4, 256, 0, stream>>>(cnt, bucket, dinv, h0, gb0, bn0g, bn0b,
                                          W1, h1);
    k_gatherB<<<NN / 4, 256, 0, stream>>>(cnt, bucket, dinv, h1, gb1, bn1g, bn1b, x2);

    // ---- transpose x2 for coalesced gfeat ----
    k_xpose<<<NN / 64, 256, 0, stream>>>(x2, x2t);

    // ---- temporal (fused conv1 + concat + conv2 + BN2d, packed fp32) -> bf16 Ab ----
    hipMemsetAsync(Ab, 0, (size_t)BATCH * KP1 * 2, stream);  // zero K-padding
    k_temporal2<<<NN / 16, 256, 0, stream>>>(data_x, x2t, tc1w1, tc1b1, tc1w2, tc1b2,
                                             tc1w3, tc1b3, tc2w1, tc2b1, tc2w2, tc2b2,
                                             tc2w3, tc2b3, bn2g, bn2b, Ab);

    // ---- FC (bf16 MFMA) ----
    {
        dim3 g(FC1_OUT / 64, KSPL1);
        k_gemm1f<<<g, 256, 0, stream>>>(Ab, fcW, part1);
    }
    k_reduce1<<<BATCH * FC1_OUT / 256, 256, 0, stream>>>(part1, fcb, Ab2);
    {
        dim3 g((NP2 + 31) / 32, FC1_OUT / 32);
        k_cvtW4<<<g, 256, 0, stream>>>(fc4W, W4t);
    }
    {
        dim3 g(NP2 / 16, KSPL2);
        k_gemm2<<<g, 256, 0, stream>>>(Ab2, W4t, part2);
    }
    k_reduce2<<<(BATCH * NP2 + 255) / 256, 256, 0, stream>>>(part2, fc4b, out);
}

// Round 10
// 190.697 us; speedup vs baseline: 2.1907x; 1.0788x over previous
//
#include <hip/hip_runtime.h>

#define NODES   304
#define BATCH   128
#define TSTEPS  20
#define HID     64
#define GCNIN   20
#define NN      (BATCH*NODES)      // 38912
#define NE      (NN*16)            // 622592
#define SEGSZ   (NN/4)             // 9728 (row-quarter for L2 phasing)
#define BCAP    64                 // bucket capacity per col
#define FC1_IN  (21*NODES)         // 6384
#define KP1     6400               // FC1_IN padded to /32
#define FC1_OUT 2048
#define FC2_OUT 300
#define NP2     304                // FC2_OUT padded to /16
#define BN_EPS  1e-5f

typedef __attribute__((ext_vector_type(8))) short short8;
typedef __attribute__((ext_vector_type(4))) float f32x4;
typedef __attribute__((ext_vector_type(2))) float f32x2;

static __device__ __forceinline__ short f2bf(float x) {
    unsigned u = __float_as_uint(x);
    unsigned r = (u + 0x7FFF + ((u >> 16) & 1)) >> 16;  // RNE
    return (short)r;
}
static __device__ __forceinline__ float bf2f(unsigned short v) {
    return __uint_as_float((unsigned)v << 16);
}

static __device__ __forceinline__ float fast_sigmoid(float q) {
    return __builtin_amdgcn_rcpf(1.f + __expf(-q));
}

// packed fp32 FMA (VOP3P)
static __device__ __forceinline__ f32x2 pk_fma(f32x2 a, f32x2 b, f32x2 c) {
    f32x2 d;
    asm("v_pk_fma_f32 %0, %1, %2, %3" : "=v"(d) : "v"(a), "v"(b), "v"(c));
    return d;
}

// DPP row_ror add (VALU pipe, no DS ops)
template <int C>
static __device__ __forceinline__ float dppadd(float v) {
    return v + __int_as_float(
        __builtin_amdgcn_update_dpp(0, __float_as_int(v), C, 0xF, 0xF, false));
}
static __device__ __forceinline__ float rsum16(float v) {
    v = dppadd<0x128>(v);
    v = dppadd<0x124>(v);
    v = dppadd<0x122>(v);
    v = dppadd<0x121>(v);
    return v;
}

// ---------------- bucketed edge build: ONE global atomic per edge ----------------
__global__ void k_bucket(const int* __restrict__ ei, const float* __restrict__ ew,
                         int* __restrict__ cnt, int2* __restrict__ bucket) {
    int e = blockIdx.x * blockDim.x + threadIdx.x;
    if (e < NE) {
        int c = ei[NE + e];
        int slot = atomicAdd(&cnt[c], 1);
        if (slot < BCAP) {
            int2 v;
            v.x = ei[e];
            v.y = __float_as_int(ew[e]);
            bucket[((size_t)c << 6) + slot] = v;
        }
    }
}

// ---- Xb = dinv * data_x as bf16 [NN][32] (64B rows); also computes dinv ----
__global__ __launch_bounds__(256) void k_cvtX(const float* __restrict__ X,
                                              const int* __restrict__ cnt,
                                              const int2* __restrict__ bucket,
                                              unsigned short* __restrict__ Xb,
                                              float* __restrict__ dinv) {
    int wv = threadIdx.x >> 5, f = threadIdx.x & 31;  // 8 nodes x 32 lanes
    int n = blockIdx.x * 8 + wv;
    __shared__ float rs[8][2];

    // issue independent loads up front
    int2 e0 = bucket[((size_t)n << 6) + f];
    int2 e1 = bucket[((size_t)n << 6) + 32 + f];
    int deg = cnt[n];
    float xv = (f < GCNIN) ? X[(size_t)n * GCNIN + f] : 0.f;

    int dcap = deg < BCAP ? deg : BCAP;
    float s = ((f < dcap) ? __int_as_float(e0.y) : 0.f) +
              ((32 + f < dcap) ? __int_as_float(e1.y) : 0.f);
    s = rsum16(s);
    if ((f & 15) == 0) rs[wv][f >> 4] = s;
    __syncthreads();

    float dv = rsqrtf(fmaxf(1.f + rs[wv][0] + rs[wv][1], 1e-12f));
    if (f == 0) dinv[n] = dv;
    Xb[(size_t)n * 32 + f] = (f < GCNIN) ? (unsigned short)f2bf(xv * dv)
                                         : (unsigned short)0;
}

// ballot-partition the wave's staged edges by row-quarter (L2 phasing)
static __device__ __forceinline__ void stage_partition(
    int deg, int2 e, int f, int wv, int (*sIdx)[BCAP], float (*sWt)[BCAP],
    int& dcap) {
    dcap = deg < BCAP ? deg : BCAP;
    bool valid = f < dcap;
    int row = e.x;
    float w = __int_as_float(e.y);
    int q = (row >= SEGSZ) + (row >= 2 * SEGSZ) + (row >= 3 * SEGSZ);
    unsigned long long b0 = __ballot(valid && q == 0);
    unsigned long long b1 = __ballot(valid && q == 1);
    unsigned long long b2 = __ballot(valid && q == 2);
    unsigned long long b3 = __ballot(valid && q == 3);
    unsigned long long lmask = (1ULL << f) - 1;
    int pos = 0;
    if (q > 0) pos += __popcll(b0);
    if (q > 1) pos += __popcll(b1);
    if (q > 2) pos += __popcll(b2);
    unsigned long long mybal = (q == 0) ? b0 : (q == 1) ? b1 : (q == 2) ? b2 : b3;
    pos += __popcll(mybal & lmask);
    if (valid) {
        sIdx[wv][pos] = row;
        sWt[wv][pos] = w;
    }
}

// ---- layer0: gather RAW 20-dim feats (L2-resident 2.5MB table) + @W0 + BN +
//      ReLU + matvec @W1 -> h1 prescaled bf16 ----
__global__ __launch_bounds__(256) void k_gather20(const int* __restrict__ cnt,
                                                  const int2* __restrict__ bucket,
                                                  const float* __restrict__ dinv,
                                                  const unsigned short* __restrict__ Xb,
                                                  const float* __restrict__ W0,
                                                  const float* __restrict__ gb,
                                                  const float* __restrict__ bng,
                                                  const float* __restrict__ bnb,
                                                  const float* __restrict__ W1,
                                                  unsigned short* __restrict__ H1) {
    int wv = threadIdx.x >> 6, f = threadIdx.x & 63;
    int c = blockIdx.x * 4 + wv;
    int g = f >> 4, r = f & 15;  // edge-group, channel-pair lane
    __shared__ int sIdx[4][BCAP];
    __shared__ float sWt[4][BCAP];
    __shared__ float agg[4][32];
    __shared__ float xs[4][HID];

    // issue block-start loads in parallel
    int2 be = bucket[((size_t)c << 6) + f];
    int deg = cnt[c];
    float dc = dinv[c];
    unsigned selfv = *(const unsigned*)(Xb + (size_t)c * 32 + 2 * r);

    int dcap;
    stage_partition(deg, be, f, wv, sIdx, sWt, dcap);
    __syncthreads();

    // gather: lane (g,r) covers edges base+4i+g, channels (2r, 2r+1)
    f32x2 acc2;
    acc2[0] = 0.f;
    acc2[1] = 0.f;
    for (int base = 0; base < dcap; base += 16) {
        int idx[4];
        float w[4];
#pragma unroll
        for (int i = 0; i < 4; i++) {
            int l = base + (i << 2) + g;
            int lc = (l < dcap) ? l : dcap - 1;
            idx[i] = sIdx[wv][lc];
            w[i] = (l < dcap) ? sWt[wv][lc] : 0.f;
        }
        unsigned vv[4];
#pragma unroll
        for (int i = 0; i < 4; i++)
            vv[i] = *(const unsigned*)(Xb + (size_t)idx[i] * 32 + 2 * r);
#pragma unroll
        for (int i = 0; i < 4; i++) {
            acc2[0] = fmaf(bf2f((unsigned short)(vv[i] & 0xffff)), w[i], acc2[0]);
            acc2[1] = fmaf(bf2f((unsigned short)(vv[i] >> 16)), w[i], acc2[1]);
        }
    }
    // combine the 4 edge-groups
    acc2[0] += __shfl_xor(acc2[0], 16);
    acc2[0] += __shfl_xor(acc2[0], 32);
    acc2[1] += __shfl_xor(acc2[1], 16);
    acc2[1] += __shfl_xor(acc2[1], 32);
    if (g == 0) {
        agg[wv][2 * r] = acc2[0] + bf2f((unsigned short)(selfv & 0xffff));
        agg[wv][2 * r + 1] = acc2[1] + bf2f((unsigned short)(selfv >> 16));
    }
    __syncthreads();

    // x1[f] = relu(bn((agg @ W0) * dc + gb))
    float v = 0.f;
#pragma unroll
    for (int k = 0; k < GCNIN; k++) v = fmaf(agg[wv][k], W0[k * HID + f], v);
    float scale = bng[f] * rsqrtf(1.f + BN_EPS);
    float y = fmaxf(fmaf(v * dc + gb[f], scale, bnb[f]), 0.f);

    xs[wv][f] = y;
    __syncthreads();
    float h = 0.f;
#pragma unroll
    for (int k4 = 0; k4 < HID / 4; k4++) {
        float4 xv = *(const float4*)&xs[wv][k4 * 4];
        h = fmaf(xv.x, W1[(k4 * 4 + 0) * HID + f], h);
        h = fmaf(xv.y, W1[(k4 * 4 + 1) * HID + f], h);
        h = fmaf(xv.z, W1[(k4 * 4 + 2) * HID + f], h);
        h = fmaf(xv.w, W1[(k4 * 4 + 3) * HID + f], h);
    }
    H1[(size_t)c * HID + f] = (unsigned short)f2bf(h * dc);  // pre-scaled
}

// -------- layer1 gather (ushort4 loads, 4 edge-groups) + BN + ReLU -> x2 f32 -----
__global__ __launch_bounds__(256) void k_gatherB(const int* __restrict__ cnt,
                                                 const int2* __restrict__ bucket,
                                                 const float* __restrict__ dinv,
                                                 const unsigned short* __restrict__ H,
                                                 const float* __restrict__ gb,
                                                 const float* __restrict__ bng,
                                                 const float* __restrict__ bnb,
                                                 float* __restrict__ XO) {
    int wv = threadIdx.x >> 6, f = threadIdx.x & 63;
    int c = blockIdx.x * 4 + wv;
    int g = f >> 4, r = f & 15;  // edge-group, channel-quad lane
    __shared__ int sIdx[4][BCAP];
    __shared__ float sWt[4][BCAP];

    int2 be = bucket[((size_t)c << 6) + f];
    int deg = cnt[c];
    float dc = dinv[c];
    ushort4 selfv = *(const ushort4*)(H + (size_t)c * HID + 4 * r);

    int dcap;
    stage_partition(deg, be, f, wv, sIdx, sWt, dcap);
    __syncthreads();

    float a0 = 0.f, a1 = 0.f, a2 = 0.f, a3 = 0.f;
    for (int base = 0; base < dcap; base += 16) {
        int idx[4];
        float w[4];
#pragma unroll
        for (int i = 0; i < 4; i++) {
            int l = base + (i << 2) + g;
            int lc = (l < dcap) ? l : dcap - 1;
            idx[i] = sIdx[wv][lc];
            w[i] = (l < dcap) ? sWt[wv][lc] : 0.f;
        }
        ushort4 hv[4];
#pragma unroll
        for (int i = 0; i < 4; i++)
            hv[i] = *(const ushort4*)(H + (size_t)idx[i] * HID + 4 * r);
#pragma unroll
        for (int i = 0; i < 4; i++) {
            a0 = fmaf(bf2f(hv[i].x), w[i], a0);
            a1 = fmaf(bf2f(hv[i].y), w[i], a1);
            a2 = fmaf(bf2f(hv[i].z), w[i], a2);
            a3 = fmaf(bf2f(hv[i].w), w[i], a3);
        }
    }
    a0 += __shfl_xor(a0, 16); a0 += __shfl_xor(a0, 32);
    a1 += __shfl_xor(a1, 16); a1 += __shfl_xor(a1, 32);
    a2 += __shfl_xor(a2, 16); a2 += __shfl_xor(a2, 32);
    a3 += __shfl_xor(a3, 16); a3 += __shfl_xor(a3, 32);

    if (g == 0) {
        float4 scv = *(const float4*)&bng[4 * r];
        float4 bbv = *(const float4*)&bnb[4 * r];
        float4 gbv = *(const float4*)&gb[4 * r];
        float rr = rsqrtf(1.f + BN_EPS);
        float4 o;
        o.x = fmaxf(fmaf((a0 + bf2f(selfv.x)) * dc + gbv.x, scv.x * rr, bbv.x), 0.f);
        o.y = fmaxf(fmaf((a1 + bf2f(selfv.y)) * dc + gbv.y, scv.y * rr, bbv.y), 0.f);
        o.z = fmaxf(fmaf((a2 + bf2f(selfv.z)) * dc + gbv.z, scv.z * rr, bbv.z), 0.f);
        o.w = fmaxf(fmaf((a3 + bf2f(selfv.w)) * dc + gbv.w, scv.w * rr, bbv.w), 0.f);
        *(float4*)(XO + (size_t)c * HID + 4 * r) = o;
    }
}

// ---------------- x2 [38912][64] -> x2t [64][38912] ----------------
__global__ __launch_bounds__(256) void k_xpose(const float* __restrict__ x2,
                                               float* __restrict__ x2t) {
    __shared__ float tile[64][65];
    int n0 = blockIdx.x * 64;
    for (int i = threadIdx.x; i < 4096; i += 256) {
        int r = i >> 6, h = i & 63;
        tile[r][h] = x2[(size_t)(n0 + r) * 64 + h];
    }
    __syncthreads();
    for (int i = threadIdx.x; i < 4096; i += 256) {
        int h = i >> 6, c = i & 63;
        x2t[(size_t)h * NN + n0 + c] = tile[c][h];
    }
}

// unpack 12 contiguous LDS floats (ch c0..c0+3 × 3 taps) into packed pairs
static __device__ __forceinline__ void load12(const float* base, f32x2 P[2][3]) {
    float4 f0 = *(const float4*)(base);
    float4 f1 = *(const float4*)(base + 4);
    float4 f2 = *(const float4*)(base + 8);
    P[0][0][0] = f0.x; P[0][0][1] = f0.w;
    P[0][1][0] = f0.y; P[0][1][1] = f1.x;
    P[0][2][0] = f0.z; P[0][2][1] = f1.y;
    P[1][0][0] = f1.z; P[1][0][1] = f2.y;
    P[1][1][0] = f1.w; P[1][1][1] = f2.z;
    P[1][2][0] = f2.x; P[1][2][1] = f2.w;
}

// ---------------- fused temporal: packed-fp32, LDS weights, 16 pairs/block ----
__global__ __launch_bounds__(256) void k_temporal2(
    const float* __restrict__ data_x, const float* __restrict__ x2t,
    const float* __restrict__ w1, const float* __restrict__ b1,
    const float* __restrict__ w2, const float* __restrict__ b2,
    const float* __restrict__ w3, const float* __restrict__ b3,
    const float* __restrict__ v1, const float* __restrict__ vb1,
    const float* __restrict__ v2, const float* __restrict__ vb2,
    const float* __restrict__ v3, const float* __restrict__ vb3,
    const float* __restrict__ bn2g, const float* __restrict__ bn2b,
    short* __restrict__ Ab) {
    int bn0 = blockIdx.x * 16;
    int b = bn0 / NODES, node0 = bn0 % NODES;
    int tid = threadIdx.x;
    int p = tid >> 4;
    int c0 = (tid & 15) << 2;
    int node = node0 + p;

    __shared__ float xs[16][22];
    __shared__ float wlds[1344];

    if (tid < 192) {
        wlds[tid] = w1[tid];
        wlds[192 + tid] = w2[tid];
        wlds[384 + tid] = w3[tid];
        wlds[576 + tid] = v1[tid];
        wlds[768 + tid] = v2[tid];
        wlds[960 + tid] = v3[tid];
    }
    if (tid < 64) {
        wlds[1152 + tid] = b1[tid];
        wlds[1216 + tid] = b2[tid];
        wlds[1280 + tid] = b3[tid];
    }
    for (int i = tid; i < 320; i += 256) {
        int t = i >> 4, pp = i & 15;
        xs[pp][t + 1] = data_x[b * (TSTEPS * NODES) + t * NODES + node0 + pp];
    }
    if (tid < 16) { xs[tid][0] = 0.f; xs[tid][21] = 0.f; }

    float cb1 = vb1[0], cb2 = vb2[0], cb3 = vb3[0];
    float s2 = bn2g[node] * rsqrtf(1.f + BN_EPS);
    float bb2 = bn2b[node];
    short* dst = Ab + (size_t)b * KP1;

    __syncthreads();

    f32x2 A1p[2][3], A2p[2][3], A3p[2][3], B1p[2], B2p[2], B3p[2];
    f32x2 U1p[2][3], U2p[2][3], U3p[2][3];
    load12(&wlds[0 + c0 * 3], A1p);
    load12(&wlds[192 + c0 * 3], A2p);
    load12(&wlds[384 + c0 * 3], A3p);
    load12(&wlds[576 + c0 * 3], U1p);
    load12(&wlds[768 + c0 * 3], U2p);
    load12(&wlds[960 + c0 * 3], U3p);
    {
        float4 t1 = *(const float4*)&wlds[1152 + c0];
        float4 t2 = *(const float4*)&wlds[1216 + c0];
        float4 t3 = *(const float4*)&wlds[1280 + c0];
        B1p[0][0] = t1.x; B1p[0][1] = t1.y; B1p[1][0] = t1.z; B1p[1][1] = t1.w;
        B2p[0][0] = t2.x; B2p[0][1] = t2.y; B2p[1][0] = t2.z; B2p[1][1] = t2.w;
        B3p[0][0] = t3.x; B3p[0][1] = t3.y; B3p[1][0] = t3.z; B3p[1][1] = t3.w;
    }

    f32x2 hA2[2] = {}, hB2[2] = {}, hC2[2];
    float xr0 = xs[p][0], xr1 = xs[p][1];

#pragma unroll
    for (int j = 0; j <= 21; j++) {
        if (j < 20) {
            float xr2 = xs[p][j + 2];
            f32x2 x0d, x1d, x2d;
            x0d[0] = xr0; x0d[1] = xr0;
            x1d[0] = xr1; x1d[1] = xr1;
            x2d[0] = xr2; x2d[1] = xr2;
#pragma unroll
            for (int cp = 0; cp < 2; cp++) {
                f32x2 pv = pk_fma(A1p[cp][2], x2d,
                            pk_fma(A1p[cp][1], x1d, pk_fma(A1p[cp][0], x0d, B1p[cp])));
                f32x2 qv = pk_fma(A2p[cp][2], x2d,
                            pk_fma(A2p[cp][1], x1d, pk_fma(A2p[cp][0], x0d, B2p[cp])));
                f32x2 rv = pk_fma(A3p[cp][2], x2d,
                            pk_fma(A3p[cp][1], x1d, pk_fma(A3p[cp][0], x0d, B3p[cp])));
                hC2[cp][0] = fmaxf(fmaf(pv[0], fast_sigmoid(qv[0]), rv[0]), 0.f);
                hC2[cp][1] = fmaxf(fmaf(pv[1], fast_sigmoid(qv[1]), rv[1]), 0.f);
            }
            xr0 = xr1;
            xr1 = xr2;
        } else if (j == 20) {
            const float4 gv = *(const float4*)(x2t + (size_t)(b >> 1) * NN +
                                               (b & 1) * (NODES * HID) + node * HID + c0);
            hC2[0][0] = fmaxf(gv.x, 0.f);
            hC2[0][1] = fmaxf(gv.y, 0.f);
            hC2[1][0] = fmaxf(gv.z, 0.f);
            hC2[1][1] = fmaxf(gv.w, 0.f);
        } else {
            hC2[0][0] = 0.f; hC2[0][1] = 0.f;
            hC2[1][0] = 0.f; hC2[1][1] = 0.f;
        }
        if (j >= 1) {
            int w = j - 1;
            f32x2 pa, qa, ra;
            pa[0] = 0.f; pa[1] = 0.f;
            qa[0] = 0.f; qa[1] = 0.f;
            ra[0] = 0.f; ra[1] = 0.f;
#pragma unroll
            for (int cp = 0; cp < 2; cp++) {
                pa = pk_fma(U1p[cp][0], hA2[cp], pa);
                pa = pk_fma(U1p[cp][1], hB2[cp], pa);
                pa = pk_fma(U1p[cp][2], hC2[cp], pa);
                qa = pk_fma(U2p[cp][0], hA2[cp], qa);
                qa = pk_fma(U2p[cp][1], hB2[cp], qa);
                qa = pk_fma(U2p[cp][2], hC2[cp], qa);
                ra = pk_fma(U3p[cp][0], hA2[cp], ra);
                ra = pk_fma(U3p[cp][1], hB2[cp], ra);
                ra = pk_fma(U3p[cp][2], hC2[cp], ra);
            }
            float pp_ = rsum16(pa[0] + pa[1]);
            float qq_ = rsum16(qa[0] + qa[1]);
            float rr_ = rsum16(ra[0] + ra[1]);
            float P = pp_ + cb1, Q = qq_ + cb2, R = rr_ + cb3;
            float hv = fmaxf(fmaf(P, fast_sigmoid(Q), R), 0.f);
            if ((tid & 15) == 0) dst[w * NODES + node] = f2bf(fmaf(hv, s2, bb2));
        }
        hA2[0] = hB2[0]; hA2[1] = hB2[1];
        hB2[0] = hC2[0]; hB2[1] = hC2[1];
    }
}

// fc4W [2048][300] f32 -> W4t [304][2048] bf16 (transposed, N-padded)
__global__ __launch_bounds__(256) void k_cvtW4(const float* __restrict__ W,
                                               short* __restrict__ Wt) {
    __shared__ float t[32][33];
    int tx = threadIdx.x & 31, ty = threadIdx.x >> 5;
    int n0 = blockIdx.x * 32, k0 = blockIdx.y * 32;
#pragma unroll
    for (int r = 0; r < 32; r += 8) {
        int k = k0 + r + ty, n = n0 + tx;
        t[r + ty][tx] = (n < FC2_OUT) ? W[(size_t)k * FC2_OUT + n] : 0.f;
    }
    __syncthreads();
#pragma unroll
    for (int r = 0; r < 32; r += 8) {
        int n = n0 + r + ty;
        if (n < NP2) Wt[(size_t)n * FC1_OUT + k0 + tx] = f2bf(t[tx][r + ty]);
    }
}

// ---------------- FC1 MFMA GEMM, B read directly from f32 fcW ----------------
#define KSPL1 8
#define KCH1  (KP1 / KSPL1)  // 800
__global__ __launch_bounds__(256) void k_gemm1f(const short* __restrict__ Ab,
                                                const float* __restrict__ fcW,
                                                float* __restrict__ part) {
    int lane = threadIdx.x & 63, wv = threadIdx.x >> 6;
    int r = lane & 15, kg = lane >> 4;
    int nb = blockIdx.x * 64, sp = blockIdx.y;

    f32x4 acc[2][4] = {};
    const short* a0 = Ab + (size_t)(wv * 32 + r) * KP1;
    const short* a1 = a0 + (size_t)16 * KP1;

    int k0 = sp * KCH1 + kg * 8;
    const float* wp = fcW + (size_t)k0 * FC1_OUT + nb + r;
    bool tailblk = (sp == KSPL1 - 1);

#pragma unroll 1
    for (int s = 0; s < KCH1 / 32; s++, k0 += 32) {
        short8 av0 = *(const short8*)(a0 + k0);
        short8 av1 = *(const short8*)(a1 + k0);
        short8 bv[4];
        if (tailblk && s == KCH1 / 32 - 1) {
#pragma unroll
            for (int f = 0; f < 4; f++)
#pragma unroll
                for (int i = 0; i < 8; i++) {
                    float v = (k0 + i < FC1_IN) ? wp[(size_t)i * FC1_OUT + f * 16] : 0.f;
                    bv[f][i] = f2bf(v);
                }
        } else {
#pragma unroll
            for (int f = 0; f < 4; f++)
#pragma unroll
                for (int i = 0; i < 8; i++)
                    bv[f][i] = f2bf(wp[(size_t)i * FC1_OUT + f * 16]);
        }
        acc[0][0] = __builtin_amdgcn_mfma_f32_16x16x32_bf16(av0, bv[0], acc[0][0], 0, 0, 0);
        acc[1][0] = __builtin_amdgcn_mfma_f32_16x16x32_bf16(av1, bv[0], acc[1][0], 0, 0, 0);
        acc[0][1] = __builtin_amdgcn_mfma_f32_16x16x32_bf16(av0, bv[1], acc[0][1], 0, 0, 0);
        acc[1][1] = __builtin_amdgcn_mfma_f32_16x16x32_bf16(av1, bv[1], acc[1][1], 0, 0, 0);
        acc[0][2] = __builtin_amdgcn_mfma_f32_16x16x32_bf16(av0, bv[2], acc[0][2], 0, 0, 0);
        acc[1][2] = __builtin_amdgcn_mfma_f32_16x16x32_bf16(av1, bv[2], acc[1][2], 0, 0, 0);
        acc[0][3] = __builtin_amdgcn_mfma_f32_16x16x32_bf16(av0, bv[3], acc[0][3], 0, 0, 0);
        acc[1][3] = __builtin_amdgcn_mfma_f32_16x16x32_bf16(av1, bv[3], acc[1][3], 0, 0, 0);
        wp += (size_t)32 * FC1_OUT;
    }

    float* dst = part + (size_t)sp * BATCH * FC1_OUT;
#pragma unroll
    for (int m = 0; m < 2; m++)
#pragma unroll
        for (int f = 0; f < 4; f++)
#pragma unroll
            for (int j = 0; j < 4; j++) {
                int row = wv * 32 + m * 16 + kg * 4 + j;
                int col = nb + f * 16 + r;
                dst[(size_t)row * FC1_OUT + col] = acc[m][f][j];
            }
}

// reduce split-K + bias + ReLU -> bf16 activations for FC2
__global__ __launch_bounds__(256) void k_reduce1(const float* __restrict__ part,
                                                 const float* __restrict__ bias,
                                                 short* __restrict__ Ab2) {
    int idx = blockIdx.x * 256 + threadIdx.x;
    int o = idx & (FC1_OUT - 1);
    float s = bias[o];
#pragma unroll
    for (int sp = 0; sp < KSPL1; sp++) s += part[(size_t)sp * BATCH * FC1_OUT + idx];
    Ab2[idx] = f2bf(fmaxf(s, 0.f));
}

// ---------------- FC2 MFMA GEMM ----------------
#define KSPL2 8
#define KCH2  (FC1_OUT / KSPL2)  // 256
__global__ __launch_bounds__(256) void k_gemm2(const short* __restrict__ Ab,
                                               const short* __restrict__ Wt,
                                               float* __restrict__ part) {
    int lane = threadIdx.x & 63, wv = threadIdx.x >> 6;
    int r = lane & 15, kg = lane >> 4;
    int nb = blockIdx.x * 16, sp = blockIdx.y;

    f32x4 acc[2] = {};
    const short* a0 = Ab + (size_t)(wv * 32 + r) * FC1_OUT;
    const short* a1 = a0 + (size_t)16 * FC1_OUT;
    const short* bp = Wt + (size_t)(nb + r) * FC1_OUT;

    int k0 = sp * KCH2 + kg * 8;
#pragma unroll
    for (int s = 0; s < KCH2 / 32; s++, k0 += 32) {
        short8 av0 = *(const short8*)(a0 + k0);
        short8 av1 = *(const short8*)(a1 + k0);
        short8 bv = *(const short8*)(bp + k0);
        acc[0] = __builtin_amdgcn_mfma_f32_16x16x32_bf16(av0, bv, acc[0], 0, 0, 0);
        acc[1] = __builtin_amdgcn_mfma_f32_16x16x32_bf16(av1, bv, acc[1], 0, 0, 0);
    }

    float* dst = part + (size_t)sp * BATCH * NP2;
#pragma unroll
    for (int m = 0; m < 2; m++)
#pragma unroll
        for (int j = 0; j < 4; j++) {
            int row = wv * 32 + m * 16 + kg * 4 + j;
            int col = nb + r;
            dst[(size_t)row * NP2 + col] = acc[m][j];
        }
}

__global__ __launch_bounds__(256) void k_reduce2(const float* __restrict__ part,
                                                 const float* __restrict__ bias,
                                                 float* __restrict__ out) {
    int idx = blockIdx.x * 256 + threadIdx.x;
    if (idx >= BATCH * NP2) return;
    int b = idx / NP2, o = idx % NP2;
    float s = 0.f;
#pragma unroll
    for (int sp = 0; sp < KSPL2; sp++) s += part[(size_t)sp * BATCH * NP2 + idx];
    if (o < FC2_OUT) out[(size_t)b * FC2_OUT + o] = s + bias[o];
}

extern "C" void kernel_launch(void* const* d_in, const int* in_sizes, int n_in,
                              void* d_out, int out_size, void* d_ws, size_t ws_size,
                              hipStream_t stream) {
    const float* data_x = (const float*)d_in[0];
    const int* ei = (const int*)d_in[1];
    const float* ew = (const float*)d_in[2];
    const float* tc1w1 = (const float*)d_in[3];
    const float* tc1b1 = (const float*)d_in[4];
    const float* tc1w2 = (const float*)d_in[5];
    const float* tc1b2 = (const float*)d_in[6];
    const float* tc1w3 = (const float*)d_in[7];
    const float* tc1b3 = (const float*)d_in[8];
    const float* W0 = (const float*)d_in[9];
    const float* gb0 = (const float*)d_in[10];
    const float* bn0g = (const float*)d_in[11];
    const float* bn0b = (const float*)d_in[12];
    const float* W1 = (const float*)d_in[13];
    const float* gb1 = (const float*)d_in[14];
    const float* bn1g = (const float*)d_in[15];
    const float* bn1b = (const float*)d_in[16];
    const float* tc2w1 = (const float*)d_in[17];
    const float* tc2b1 = (const float*)d_in[18];
    const float* tc2w2 = (const float*)d_in[19];
    const float* tc2b2 = (const float*)d_in[20];
    const float* tc2w3 = (const float*)d_in[21];
    const float* tc2b3 = (const float*)d_in[22];
    const float* bn2g = (const float*)d_in[23];
    const float* bn2b = (const float*)d_in[24];
    const float* fcW = (const float*)d_in[25];
    const float* fcb = (const float*)d_in[26];
    const float* fc4W = (const float*)d_in[27];
    const float* fc4b = (const float*)d_in[28];
    float* out = (float*)d_out;

    char* ws = (char*)d_ws;
    // persistent: x2 (gfeat source) + Ab (FC1 bf16 activations)
    float* x2 = (float*)(ws + 0);                  // 9,961,472 B
    short* Ab = (short*)(ws + 9961472);            // 1,638,400 B
    const size_t ARENA = 9961472 + 1638400;        // 11,599,872

    // arena A (graph phase)
    size_t off = ARENA;
    auto alloc = [&](size_t bytes) -> void* {
        void* p = ws + off;
        off = (off + bytes + 255) & ~(size_t)255;
        return p;
    };
    int2* bucket = (int2*)alloc((size_t)NN * BCAP * 8);  // 19.9 MB
    int* cnt = (int*)alloc((size_t)NN * 4);
    float* dinv = (float*)alloc((size_t)NN * 4);
    unsigned short* Xb = (unsigned short*)alloc((size_t)NN * 32 * 2);  // 2.5 MB
    unsigned short* h1 = (unsigned short*)alloc((size_t)NN * HID * 2); // 5 MB

    // x2t overlaps arena A (bucket region dead after gatherB)
    float* x2t = (float*)(ws + ARENA);             // 9,961,472 B

    // arena C (FC phase) — overlaps arena A and x2t, used only after temporal
    off = ARENA;
    float* part1 = (float*)alloc((size_t)KSPL1 * BATCH * FC1_OUT * 4);
    short* Ab2 = (short*)alloc((size_t)BATCH * FC1_OUT * 2);
    short* W4t = (short*)alloc((size_t)NP2 * FC1_OUT * 2);
    float* part2 = (float*)alloc((size_t)KSPL2 * BATCH * NP2 * 4);
    (void)ws_size; (void)in_sizes; (void)n_in; (void)out_size;

    // ---- bucketed edge build ----
    hipMemsetAsync(cnt, 0, (size_t)NN * 4, stream);
    k_bucket<<<(NE + 255) / 256, 256, 0, stream>>>(ei, ew, cnt, bucket);

    // ---- GCN: cvtX (dinv + prescaled 20-dim bf16 table), then gathers ----
    k_cvtX<<<NN / 8, 256, 0, stream>>>(data_x, cnt, bucket, Xb, dinv);
    k_gather20<<<NN / 4, 256, 0, stream>>>(cnt, bucket, dinv, Xb, W0, gb0, bn0g,
                                           bn0b, W1, h1);
    k_gatherB<<<NN / 4, 256, 0, stream>>>(cnt, bucket, dinv, h1, gb1, bn1g, bn1b, x2);

    // ---- transpose x2 for coalesced gfeat ----
    k_xpose<<<NN / 64, 256, 0, stream>>>(x2, x2t);

    // ---- temporal (fused conv1 + concat + conv2 + BN2d, packed fp32) -> bf16 Ab ----
    hipMemsetAsync(Ab, 0, (size_t)BATCH * KP1 * 2, stream);  // zero K-padding
    k_temporal2<<<NN / 16, 256, 0, stream>>>(data_x, x2t, tc1w1, tc1b1, tc1w2, tc1b2,
                                             tc1w3, tc1b3, tc2w1, tc2b1, tc2w2, tc2b2,
                                             tc2w3, tc2b3, bn2g, bn2b, Ab);

    // ---- FC (bf16 MFMA) ----
    {
        dim3 g(FC1_OUT / 64, KSPL1);
        k_gemm1f<<<g, 256, 0, stream>>>(Ab, fcW, part1);
    }
    k_reduce1<<<BATCH * FC1_OUT / 256, 256, 0, stream>>>(part1, fcb, Ab2);
    {
        dim3 g((NP2 + 31) / 32, FC1_OUT / 32);
        k_cvtW4<<<g, 256, 0, stream>>>(fc4W, W4t);
    }
    {
        dim3 g(NP2 / 16, KSPL2);
        k_gemm2<<<g, 256, 0, stream>>>(Ab2, W4t, part2);
    }
    k_reduce2<<<(BATCH * NP2 + 255) / 256, 256, 0, stream>>>(part2, fc4b, out);
}